// Round 5
// baseline (568.535 us; speedup 1.0000x reference)
//
#include <hip/hip_runtime.h>
#include <hip/hip_fp16.h>

#define BB 4
#define NN 120000
#define FEAT 128
#define HH 128
#define WW 128
#define NPTS (BB*NN)
#define HW (HH*WW)

// ---- ws layout (4-byte element offsets) ----
#define OW1    0         // f32[256]  [o=64][i=4]
#define OB1    256       // f32[64]
#define OW2P   320       // u32[4096] packed half2 [r=32][o=128]
#define OB2    4416      // f32[128]
#define OW3P   4544      // u32[8192] packed half2 [chunk=16][r=64][j=8]
#define OB3    12736     // f32[128]
#define OCNT   12864     // i32[65536]
#define OOFF   78400     // i32[65536]
#define ONV    143936    // i32[1] (padded to 64)
#define OCELLS 144000    // i32[NPTS]
#define OSIDX  624000    // i32[NPTS]
#define OSCELL 1104000   // i32[NPTS]
#define OBEV   1584000   // fallback: f32[BB*HW*128]
#define OFEATS 1584000   // A path: u32[NPTS*64]
#define BEV_ELEMS (BB*HW*FEAT)

#if defined(__has_builtin)
#if __has_builtin(__builtin_amdgcn_fdot2)
#define HAS_FDOT2 1
#endif
#endif

typedef _Float16 hv2 __attribute__((ext_vector_type(2)));

__device__ __forceinline__ unsigned pk2(float a, float b) {
    __half2 h = __floats2half2_rn(a, b);
    return __builtin_bit_cast(unsigned, h);
}

__device__ __forceinline__ float dot2(unsigned a, unsigned b, float c) {
#ifdef HAS_FDOT2
    return __builtin_amdgcn_fdot2(__builtin_bit_cast(hv2, a),
                                  __builtin_bit_cast(hv2, b), c, false);
#else
    __half2 ah = __builtin_bit_cast(__half2, a), bh = __builtin_bit_cast(__half2, b);
    c = fmaf(__low2float(ah), __low2float(bh), c);
    return fmaf(__high2float(ah), __high2float(bh), c);
#endif
}

// All stored feature values are post-ReLU (>= 0), so fp16 bit patterns order
// as unsigned 16-bit ints: packed fp16 max == per-halfword unsigned max.
__device__ __forceinline__ unsigned hmax2u(unsigned a, unsigned b) {
    unsigned al = a & 0xFFFFu, bl = b & 0xFFFFu;
    unsigned ah = a & 0xFFFF0000u, bh = b & 0xFFFF0000u;
    unsigned lo = (al > bl) ? al : bl;
    unsigned hi = (ah > bh) ? ah : bh;
    return lo | hi;
}

// ---------------- weight folding + fp16 packing ----------------
__global__ void fold_weights_k(
    const float* __restrict__ W1, const float* __restrict__ b1,
    const float* __restrict__ g1, const float* __restrict__ be1,
    const float* __restrict__ m1, const float* __restrict__ v1,
    const float* __restrict__ W2, const float* __restrict__ b2,
    const float* __restrict__ g2, const float* __restrict__ be2,
    const float* __restrict__ m2, const float* __restrict__ v2,
    const float* __restrict__ W3, const float* __restrict__ b3,
    const float* __restrict__ g3, const float* __restrict__ be3,
    const float* __restrict__ m3, const float* __restrict__ v3,
    float* __restrict__ wf)
{
    unsigned* wu = (unsigned*)wf;
    int idx = blockIdx.x * 256 + threadIdx.x;
    const float EPSV = 1e-5f;
    if (idx < 256) {
        int o = idx >> 2;
        float s = g1[o] * rsqrtf(v1[o] + EPSV);
        wf[OW1 + idx] = W1[idx] * s;
    } else if (idx < 320) {
        int o = idx - 256;
        float s = g1[o] * rsqrtf(v1[o] + EPSV);
        wf[idx] = (b1[o] - m1[o]) * s + be1[o];
    } else if (idx < 4416) {
        int j = idx - OW2P;
        int r = j >> 7, o = j & 127;
        float s = g2[o] * rsqrtf(v2[o] + EPSV);
        wu[idx] = pk2(W2[o * 64 + 2 * r] * s, W2[o * 64 + 2 * r + 1] * s);
    } else if (idx < 4544) {
        int o = idx - OB2;
        float s = g2[o] * rsqrtf(v2[o] + EPSV);
        wf[idx] = (b2[o] - m2[o]) * s + be2[o];
    } else if (idx < 12736) {
        int j = idx - OW3P;
        int ch = j >> 9, rem = j & 511;
        int r = rem >> 3, jj = rem & 7;
        int o = ch * 8 + jj;
        float s = g3[o] * rsqrtf(v3[o] + EPSV);
        wu[idx] = pk2(W3[o * 128 + 2 * r] * s, W3[o * 128 + 2 * r + 1] * s);
    } else if (idx < 12864) {
        int o = idx - OB3;
        float s = g3[o] * rsqrtf(v3[o] + EPSV);
        wf[idx] = (b3[o] - m3[o]) * s + be3[o];
    }
}

// ---------------- sort-by-cell passes ----------------
__global__ __launch_bounds__(256)
void cells_hist_k(const float4* __restrict__ pts, int* __restrict__ cells,
                  int* __restrict__ cnt)
{
    int tid = blockIdx.x * 256 + threadIdx.x;
    float4 p = pts[tid];
    float xn = (p.x - (-50.0f)) / (50.0f - (-50.0f));
    float yn = (p.y - (-50.0f)) / (50.0f - (-50.0f));
    bool valid = (xn >= 0.0f) && (xn <= 1.0f) && (yn >= 0.0f) && (yn <= 1.0f);
    int gx = min(max((int)(xn * 127.0f), 0), 127);
    int gy = min(max((int)(yn * 127.0f), 0), 127);
    int b = tid / NN;
    int cell = valid ? (b * HW + gy * WW + gx) : -1;
    cells[tid] = cell;
    if (valid) atomicAdd(&cnt[cell], 1);
}

__global__ __launch_bounds__(1024)
void scan_k(const int* __restrict__ cnt, int* __restrict__ off, int* __restrict__ nvp)
{
    __shared__ int wsum[16];
    int t = threadIdx.x;
    int lane = t & 63, w = t >> 6;
    int base = t * 64;
    int s = 0;
#pragma unroll 8
    for (int j = 0; j < 64; ++j) s += cnt[base + j];
    int v = s;
#pragma unroll
    for (int d = 1; d < 64; d <<= 1) {
        int u = __shfl_up(v, d);
        if (lane >= d) v += u;
    }
    if (lane == 63) wsum[w] = v;
    __syncthreads();
    if (t == 0) {
        int r = 0;
#pragma unroll
        for (int k = 0; k < 16; ++k) { int x = wsum[k]; wsum[k] = r; r += x; }
        nvp[0] = r;
    }
    __syncthreads();
    int excl = (v - s) + wsum[w];
    int r = excl;
#pragma unroll 8
    for (int j = 0; j < 64; ++j) { off[base + j] = r; r += cnt[base + j]; }
}

__global__ __launch_bounds__(256)
void scatter_idx_k(const int* __restrict__ cells, int* __restrict__ off,
                   int* __restrict__ sidx, int* __restrict__ scell)
{
    int tid = blockIdx.x * 256 + threadIdx.x;
    int c = cells[tid];
    if (c >= 0) {
        int pos = atomicAdd(&off[c], 1);
        sidx[pos] = tid;
        scell[pos] = c;
    }
}

// ---------------- shared MLP device code ----------------
// Layer-2 chunk loop FULLY unrolled: every h2p index is compile-time constant,
// so h2p[] stays in VGPRs (round-3's `#pragma unroll 1` demoted it to scratch:
// VGPR_Count=40 + 237MB of spill traffic).
__device__ __forceinline__ void mlp12(const float4 p, const float* __restrict__ wf,
                                      const unsigned* __restrict__ wu,
                                      unsigned h2p[64])
{
    unsigned h1p[32];
#pragma unroll
    for (int i = 0; i < 32; ++i) {
        const float* wa = wf + OW1 + 8 * i;
        float a = wf[OB1 + 2 * i], b = wf[OB1 + 2 * i + 1];
        a = fmaf(wa[0], p.x, a); a = fmaf(wa[1], p.y, a);
        a = fmaf(wa[2], p.z, a); a = fmaf(wa[3], p.w, a);
        b = fmaf(wa[4], p.x, b); b = fmaf(wa[5], p.y, b);
        b = fmaf(wa[6], p.z, b); b = fmaf(wa[7], p.w, b);
        h1p[i] = pk2(fmaxf(a, 0.0f), fmaxf(b, 0.0f));
    }
#pragma unroll
    for (int o0 = 0; o0 < 128; o0 += 16) {
        float acc[16];
#pragma unroll
        for (int j = 0; j < 16; ++j) acc[j] = wf[OB2 + o0 + j];
#pragma unroll
        for (int r = 0; r < 32; ++r) {
            const unsigned* wr = wu + OW2P + r * 128 + o0;
#pragma unroll
            for (int j = 0; j < 16; ++j) acc[j] = dot2(h1p[r], wr[j], acc[j]);
        }
#pragma unroll
        for (int j = 0; j < 16; j += 2)
            h2p[(o0 + j) >> 1] = pk2(fmaxf(acc[j], 0.0f), fmaxf(acc[j + 1], 0.0f));
    }
}

__device__ __forceinline__ void l3chunk(int ch, const float* __restrict__ wf,
                                        const unsigned* __restrict__ wu,
                                        const unsigned h2p[64], float a[8])
{
#pragma unroll
    for (int j = 0; j < 8; ++j) a[j] = wf[OB3 + ch * 8 + j];
    const unsigned* wq = wu + OW3P + ch * 512;
#pragma unroll
    for (int r = 0; r < 64; ++r) {
#pragma unroll
        for (int j = 0; j < 8; ++j) a[j] = dot2(h2p[r], wq[r * 8 + j], a[j]);
    }
}

// ---------------- A path: MLP -> fp16 feats (no atomics, no LDS) ----------------
__global__ __launch_bounds__(256, 3)
void mlp_feats_k(const float4* __restrict__ pts, const float* __restrict__ wf,
                 const int* __restrict__ sidx, const int* __restrict__ nvp,
                 uint4* __restrict__ feats4)
{
    const unsigned* wu = (const unsigned*)wf;
    const int slot = blockIdx.x * 256 + threadIdx.x;
    const int nv = nvp[0];
    if ((slot & ~63) >= nv) return;
    const bool live = slot < nv;
    const int pidx = live ? sidx[slot] : 0;
    float4 p = pts[pidx];

    unsigned h2p[64];
    mlp12(p, wf, wu, h2p);

#pragma unroll 1
    for (int c = 0; c < 16; ++c) {
        float a[8];
        l3chunk(c, wf, wu, h2p, a);
        if (live) {
            uint4 v;
            v.x = pk2(fmaxf(a[0], 0.0f), fmaxf(a[1], 0.0f));
            v.y = pk2(fmaxf(a[2], 0.0f), fmaxf(a[3], 0.0f));
            v.z = pk2(fmaxf(a[4], 0.0f), fmaxf(a[5], 0.0f));
            v.w = pk2(fmaxf(a[6], 0.0f), fmaxf(a[7], 0.0f));
            feats4[(size_t)slot * 16 + c] = v;
        }
    }
}

// ---------------- A path: per-cell max-reduce, uint2/2-row loads ----------------
__global__ __launch_bounds__(256)
void reduce_k(const unsigned* __restrict__ feats, const int* __restrict__ off,
              const int* __restrict__ cnt, float* __restrict__ out)
{
    __shared__ float tile[128][65];
    const int tid = threadIdx.x;
    const int w = tid >> 6, l = tid & 63;
    const int l31 = l & 31, lh = l >> 5;       // row half: 0 or 1
    const int c0 = blockIdx.x * 64;
    const uint2* f2 = (const uint2*)feats;

#pragma unroll 1
    for (int cc = 0; cc < 16; ++cc) {
        int c = c0 + w * 16 + cc;
        int n = cnt[c];
        int start = off[c] - n;                // off advanced to run end by scatter
        unsigned m01 = 0u, m23 = 0u;           // packed fp16 maxes (all vals >= 0)
        // lanes 0-31: rows 2p; lanes 32-63: rows 2p+1; 32 uint2 per row
        const uint2* fp = f2 + (size_t)(start + lh) * 32 + l31;
#pragma unroll 1
        for (int p = 0; 2 * p < n; ++p) {
            if (2 * p + lh < n) {
                uint2 v = fp[(size_t)p * 64];
                m01 = hmax2u(m01, v.x);
                m23 = hmax2u(m23, v.y);
            }
        }
        m01 = hmax2u(m01, (unsigned)__shfl_xor((int)m01, 32));
        m23 = hmax2u(m23, (unsigned)__shfl_xor((int)m23, 32));
        if (lh == 0) {
            __half2 h01 = __builtin_bit_cast(__half2, m01);
            __half2 h23 = __builtin_bit_cast(__half2, m23);
            int f0 = 4 * l31, cl = w * 16 + cc;
            tile[f0 + 0][cl] = __low2float(h01);
            tile[f0 + 1][cl] = __high2float(h01);
            tile[f0 + 2][cl] = __low2float(h23);
            tile[f0 + 3][cl] = __high2float(h23);
        }
    }
    __syncthreads();
    const int b = c0 >> 14;
    const int cxy = c0 & (HW - 1);
#pragma unroll 4
    for (int k = 0; k < 32; ++k) {
        int idx = k * 256 + tid;
        int f = idx >> 6, c = idx & 63;
        out[((size_t)(b * 128 + f)) * HW + cxy + c] = tile[f][c];
    }
}

// ---------------- B path: atomic fallback (run-merged) ----------------
#define DPPMAX(A, D, S) { \
    float _pv = __int_as_float(__builtin_amdgcn_update_dpp( \
        0, __float_as_int(A), 0x110 | (D), 0xF, 0xF, false)); \
    A = (S) ? fmaxf(A, _pv) : A; }

__global__ __launch_bounds__(256, 3)
void mlp_atomic_k(const float4* __restrict__ pts, const float* __restrict__ wf,
                  const int* __restrict__ sidx, const int* __restrict__ scell,
                  const int* __restrict__ nvp, float* __restrict__ bev, int layout)
{
    const unsigned* wu = (const unsigned*)wf;
    const int tid = threadIdx.x;
    const int slot = blockIdx.x * 256 + tid;
    const int nv = nvp[0];
    if ((slot & ~63) >= nv) return;
    const int lane = tid & 63;
    const int l15 = lane & 15;
    const bool live = slot < nv;
    const int cell = live ? scell[slot] : -1;
    const int pidx = live ? sidx[slot] : 0;
    float4 p = pts[pidx];

    int c1 = __shfl_up(cell, 1), c2 = __shfl_up(cell, 2);
    int c4 = __shfl_up(cell, 4), c8 = __shfl_up(cell, 8);
    bool s1 = (l15 >= 1) && (c1 == cell);
    bool s2 = (l15 >= 2) && (c2 == cell);
    bool s4 = (l15 >= 4) && (c4 == cell);
    bool s8 = (l15 >= 8) && (c8 == cell);
    int cn = __shfl_down(cell, 1);
    bool tail = (l15 == 15) || (cn != cell);

    unsigned h2p[64];
    mlp12(p, wf, wu, h2p);

    int* ob = (int*)bev;
    long base0;
    if (layout == 0) base0 = (long)cell * 128;
    else             base0 = (long)(cell >> 14) * (128 * HW) + (cell & (HW - 1));

#pragma unroll 1
    for (int ch = 0; ch < 16; ++ch) {
        float a[8];
        l3chunk(ch, wf, wu, h2p, a);
#pragma unroll
        for (int j = 0; j < 8; ++j) {
            a[j] = fmaxf(a[j], 0.0f);
            DPPMAX(a[j], 1, s1); DPPMAX(a[j], 2, s2);
            DPPMAX(a[j], 4, s4); DPPMAX(a[j], 8, s8);
        }
        if (tail && cell >= 0) {
            if (layout == 0) {
#pragma unroll
                for (int j = 0; j < 8; ++j)
                    atomicMax(ob + base0 + ch * 8 + j, __float_as_int(a[j]));
            } else {
#pragma unroll
                for (int j = 0; j < 8; ++j)
                    atomicMax(ob + base0 + (long)(ch * 8 + j) * HW, __float_as_int(a[j]));
            }
        }
    }
}

__global__ void transpose_bev_k(const float* __restrict__ bev, float* __restrict__ out)
{
    __shared__ float tile[32][129];
    const int tid = threadIdx.x;
    const int cell0 = blockIdx.x * 32;
#pragma unroll
    for (int k = 0; k < 16; ++k) {
        int idx = k * 256 + tid;
        int c = idx >> 7, f = idx & 127;
        tile[c][f] = bev[(size_t)(cell0 + c) * 128 + f];
    }
    __syncthreads();
    const int b = cell0 >> 14;
    const int cl0 = cell0 & (HW - 1);
#pragma unroll
    for (int k = 0; k < 16; ++k) {
        int idx = k * 256 + tid;
        int f = idx >> 5, c = idx & 31;
        out[(size_t)(b * 128 + f) * HW + cl0 + c] = tile[c][f];
    }
}

extern "C" void kernel_launch(void* const* d_in, const int* in_sizes, int n_in,
                              void* d_out, int out_size, void* d_ws, size_t ws_size,
                              hipStream_t stream)
{
    const float* points = (const float*)d_in[0];
    const float* W1 = (const float*)d_in[1];  const float* b1 = (const float*)d_in[2];
    const float* g1 = (const float*)d_in[3];  const float* be1 = (const float*)d_in[4];
    const float* m1 = (const float*)d_in[5];  const float* v1 = (const float*)d_in[6];
    const float* W2 = (const float*)d_in[7];  const float* b2 = (const float*)d_in[8];
    const float* g2 = (const float*)d_in[9];  const float* be2 = (const float*)d_in[10];
    const float* m2 = (const float*)d_in[11]; const float* v2 = (const float*)d_in[12];
    const float* W3 = (const float*)d_in[13]; const float* b3 = (const float*)d_in[14];
    const float* g3 = (const float*)d_in[15]; const float* be3 = (const float*)d_in[16];
    const float* m3 = (const float*)d_in[17]; const float* v3 = (const float*)d_in[18];

    float* wsf = (float*)d_ws;
    int*   wsi = (int*)d_ws;
    const size_t need_full = ((size_t)OFEATS + (size_t)NPTS * 64) * 4;  // ~129 MB
    const size_t need_bev  = ((size_t)OBEV + BEV_ELEMS) * 4;            // ~40 MB

    fold_weights_k<<<51, 256, 0, stream>>>(
        W1, b1, g1, be1, m1, v1, W2, b2, g2, be2, m2, v2, W3, b3, g3, be3, m3, v3, wsf);

    (void)hipMemsetAsync(wsi + OCNT, 0, 65536 * sizeof(int), stream);
    cells_hist_k<<<NPTS / 256, 256, 0, stream>>>(
        (const float4*)points, wsi + OCELLS, wsi + OCNT);
    scan_k<<<1, 1024, 0, stream>>>(wsi + OCNT, wsi + OOFF, wsi + ONV);
    scatter_idx_k<<<NPTS / 256, 256, 0, stream>>>(
        wsi + OCELLS, wsi + OOFF, wsi + OSIDX, wsi + OSCELL);

    if (ws_size >= need_full) {
        uint4* feats4 = (uint4*)(wsi + OFEATS);
        mlp_feats_k<<<NPTS / 256, 256, 0, stream>>>(
            (const float4*)points, wsf, wsi + OSIDX, wsi + ONV, feats4);
        reduce_k<<<BB * HW / 64, 256, 0, stream>>>(
            (const unsigned*)feats4, wsi + OOFF, wsi + OCNT, (float*)d_out);
    } else if (ws_size >= need_bev) {
        float* bev = wsf + OBEV;
        (void)hipMemsetAsync(bev, 0, (size_t)BEV_ELEMS * sizeof(float), stream);
        mlp_atomic_k<<<NPTS / 256, 256, 0, stream>>>(
            (const float4*)points, wsf, wsi + OSIDX, wsi + OSCELL, wsi + ONV, bev, 0);
        transpose_bev_k<<<HW * BB / 32, 256, 0, stream>>>(bev, (float*)d_out);
    } else {
        (void)hipMemsetAsync(d_out, 0, (size_t)out_size * sizeof(float), stream);
        mlp_atomic_k<<<NPTS / 256, 256, 0, stream>>>(
            (const float4*)points, wsf, wsi + OSIDX, wsi + OSCELL, wsi + ONV,
            (float*)d_out, 1);
    }
}

// Round 6
// 555.196 us; speedup vs baseline: 1.0240x; 1.0240x over previous
//
#include <hip/hip_runtime.h>
#include <hip/hip_fp16.h>

#define BB 4
#define NN 120000
#define FEAT 128
#define HH 128
#define WW 128
#define NPTS (BB*NN)
#define HW (HH*WW)

// ---- ws layout (4-byte element offsets) ----
#define OW1    0         // f32[256]  [o=64][i=4]
#define OB1    256       // f32[64]
#define OW2P   320       // u32[4096] packed half2 [r=32][o=128]
#define OB2    4416      // f32[128]
#define OW3P   4544      // u32[8192] packed half2 [chunk=16][r=64][j=8]
#define OB3    12736     // f32[128]
#define OCNT   12864     // i32[65536]
#define OOFF   78400     // i32[65536]
#define ONV    143936    // i32[1] (padded to 64)
#define OCELLS 144000    // i32[NPTS]
#define OSIDX  624000    // i32[NPTS]
#define OSCELL 1104000   // i32[NPTS]
#define OBEV   1584000   // fallback: f32[BB*HW*128]
#define OFEATS 1584000   // A path: u32[NPTS*64]
#define BEV_ELEMS (BB*HW*FEAT)

#if defined(__has_builtin)
#if __has_builtin(__builtin_amdgcn_fdot2)
#define HAS_FDOT2 1
#endif
#endif

typedef _Float16 hv2 __attribute__((ext_vector_type(2)));
// ext_vector locals are whole-vector SSA values after mem2reg -> never demoted
// to scratch by AMDGPUPromoteAlloca (which rejected our 480B of C arrays:
// VGPR_Count 40/56 + 237-316MB spill traffic in rounds 3/5).
typedef unsigned uv32 __attribute__((ext_vector_type(32)));
typedef unsigned uv64 __attribute__((ext_vector_type(64)));
typedef float    fv16 __attribute__((ext_vector_type(16)));
typedef float    fv8  __attribute__((ext_vector_type(8)));

__device__ __forceinline__ unsigned pk2(float a, float b) {
    __half2 h = __floats2half2_rn(a, b);
    return __builtin_bit_cast(unsigned, h);
}

__device__ __forceinline__ float dot2(unsigned a, unsigned b, float c) {
#ifdef HAS_FDOT2
    return __builtin_amdgcn_fdot2(__builtin_bit_cast(hv2, a),
                                  __builtin_bit_cast(hv2, b), c, false);
#else
    __half2 ah = __builtin_bit_cast(__half2, a), bh = __builtin_bit_cast(__half2, b);
    c = fmaf(__low2float(ah), __low2float(bh), c);
    return fmaf(__high2float(ah), __high2float(bh), c);
#endif
}

// post-ReLU fp16 (>=0) orders as unsigned halfwords: packed max = uint max
__device__ __forceinline__ unsigned hmax2u(unsigned a, unsigned b) {
    unsigned al = a & 0xFFFFu, bl = b & 0xFFFFu;
    unsigned ah = a & 0xFFFF0000u, bh = b & 0xFFFF0000u;
    unsigned lo = (al > bl) ? al : bl;
    unsigned hi = (ah > bh) ? ah : bh;
    return lo | hi;
}

// ---------------- weight folding + fp16 packing ----------------
__global__ void fold_weights_k(
    const float* __restrict__ W1, const float* __restrict__ b1,
    const float* __restrict__ g1, const float* __restrict__ be1,
    const float* __restrict__ m1, const float* __restrict__ v1,
    const float* __restrict__ W2, const float* __restrict__ b2,
    const float* __restrict__ g2, const float* __restrict__ be2,
    const float* __restrict__ m2, const float* __restrict__ v2,
    const float* __restrict__ W3, const float* __restrict__ b3,
    const float* __restrict__ g3, const float* __restrict__ be3,
    const float* __restrict__ m3, const float* __restrict__ v3,
    float* __restrict__ wf)
{
    unsigned* wu = (unsigned*)wf;
    int idx = blockIdx.x * 256 + threadIdx.x;
    const float EPSV = 1e-5f;
    if (idx < 256) {
        int o = idx >> 2;
        float s = g1[o] * rsqrtf(v1[o] + EPSV);
        wf[OW1 + idx] = W1[idx] * s;
    } else if (idx < 320) {
        int o = idx - 256;
        float s = g1[o] * rsqrtf(v1[o] + EPSV);
        wf[idx] = (b1[o] - m1[o]) * s + be1[o];
    } else if (idx < 4416) {
        int j = idx - OW2P;
        int r = j >> 7, o = j & 127;
        float s = g2[o] * rsqrtf(v2[o] + EPSV);
        wu[idx] = pk2(W2[o * 64 + 2 * r] * s, W2[o * 64 + 2 * r + 1] * s);
    } else if (idx < 4544) {
        int o = idx - OB2;
        float s = g2[o] * rsqrtf(v2[o] + EPSV);
        wf[idx] = (b2[o] - m2[o]) * s + be2[o];
    } else if (idx < 12736) {
        int j = idx - OW3P;
        int ch = j >> 9, rem = j & 511;
        int r = rem >> 3, jj = rem & 7;
        int o = ch * 8 + jj;
        float s = g3[o] * rsqrtf(v3[o] + EPSV);
        wu[idx] = pk2(W3[o * 128 + 2 * r] * s, W3[o * 128 + 2 * r + 1] * s);
    } else if (idx < 12864) {
        int o = idx - OB3;
        float s = g3[o] * rsqrtf(v3[o] + EPSV);
        wf[idx] = (b3[o] - m3[o]) * s + be3[o];
    }
}

// ---------------- sort-by-cell passes ----------------
__global__ __launch_bounds__(256)
void cells_hist_k(const float4* __restrict__ pts, int* __restrict__ cells,
                  int* __restrict__ cnt)
{
    int tid = blockIdx.x * 256 + threadIdx.x;
    float4 p = pts[tid];
    float xn = (p.x - (-50.0f)) / (50.0f - (-50.0f));
    float yn = (p.y - (-50.0f)) / (50.0f - (-50.0f));
    bool valid = (xn >= 0.0f) && (xn <= 1.0f) && (yn >= 0.0f) && (yn <= 1.0f);
    int gx = min(max((int)(xn * 127.0f), 0), 127);
    int gy = min(max((int)(yn * 127.0f), 0), 127);
    int b = tid / NN;
    int cell = valid ? (b * HW + gy * WW + gx) : -1;
    cells[tid] = cell;
    if (valid) atomicAdd(&cnt[cell], 1);
}

__global__ __launch_bounds__(1024)
void scan_k(const int* __restrict__ cnt, int* __restrict__ off, int* __restrict__ nvp)
{
    __shared__ int wsum[16];
    int t = threadIdx.x;
    int lane = t & 63, w = t >> 6;
    int base = t * 64;
    int s = 0;
#pragma unroll 8
    for (int j = 0; j < 64; ++j) s += cnt[base + j];
    int v = s;
#pragma unroll
    for (int d = 1; d < 64; d <<= 1) {
        int u = __shfl_up(v, d);
        if (lane >= d) v += u;
    }
    if (lane == 63) wsum[w] = v;
    __syncthreads();
    if (t == 0) {
        int r = 0;
#pragma unroll
        for (int k = 0; k < 16; ++k) { int x = wsum[k]; wsum[k] = r; r += x; }
        nvp[0] = r;
    }
    __syncthreads();
    int excl = (v - s) + wsum[w];
    int r = excl;
#pragma unroll 8
    for (int j = 0; j < 64; ++j) { off[base + j] = r; r += cnt[base + j]; }
}

__global__ __launch_bounds__(256)
void scatter_idx_k(const int* __restrict__ cells, int* __restrict__ off,
                   int* __restrict__ sidx, int* __restrict__ scell)
{
    int tid = blockIdx.x * 256 + threadIdx.x;
    int c = cells[tid];
    if (c >= 0) {
        int pos = atomicAdd(&off[c], 1);
        sidx[pos] = tid;
        scell[pos] = c;
    }
}

// ---------------- A path: MLP -> fp16 feats, all state in ext_vectors ----------------
__global__ __launch_bounds__(256, 3)
void mlp_feats_k(const float4* __restrict__ pts, const float* __restrict__ wf,
                 const int* __restrict__ sidx, const int* __restrict__ nvp,
                 uint4* __restrict__ feats4)
{
    const unsigned* wu = (const unsigned*)wf;
    const int slot = blockIdx.x * 256 + threadIdx.x;
    const int nv = nvp[0];
    if ((slot & ~63) >= nv) return;
    const bool live = slot < nv;
    const int pidx = live ? sidx[slot] : 0;
    float4 p = pts[pidx];

    // layer 1: 4 -> 64, packed into uv32
    uv32 h1;
#pragma unroll
    for (int i = 0; i < 32; ++i) {
        const float* wa = wf + OW1 + 8 * i;
        float a = wf[OB1 + 2 * i], b = wf[OB1 + 2 * i + 1];
        a = fmaf(wa[0], p.x, a); a = fmaf(wa[1], p.y, a);
        a = fmaf(wa[2], p.z, a); a = fmaf(wa[3], p.w, a);
        b = fmaf(wa[4], p.x, b); b = fmaf(wa[5], p.y, b);
        b = fmaf(wa[6], p.z, b); b = fmaf(wa[7], p.w, b);
        h1[i] = pk2(fmaxf(a, 0.0f), fmaxf(b, 0.0f));
    }

    // layer 2: 64 -> 128; chunk loop FULLY unrolled so the h2 insert index
    // (o0+j)>>1 is a compile-time constant (dynamic vector insert would lower
    // to scratch/movrel).
    uv64 h2;
#pragma unroll
    for (int o0 = 0; o0 < 128; o0 += 16) {
        fv16 acc;
#pragma unroll
        for (int j = 0; j < 16; ++j) acc[j] = wf[OB2 + o0 + j];
#pragma unroll
        for (int r = 0; r < 32; ++r) {
            const unsigned* wr = wu + OW2P + r * 128 + o0;
#pragma unroll
            for (int j = 0; j < 16; ++j) acc[j] = dot2(h1[r], wr[j], acc[j]);
        }
#pragma unroll
        for (int j = 0; j < 16; j += 2)
            h2[(o0 + j) >> 1] = pk2(fmaxf(acc[j], 0.0f), fmaxf(acc[j + 1], 0.0f));
    }

    // layer 3: 128 -> 128; chunk loop ROLLED (I$-friendly ~530-instr body);
    // h2[r] reads are constant-indexed extracts.
#pragma unroll 1
    for (int ch = 0; ch < 16; ++ch) {
        fv8 a;
#pragma unroll
        for (int j = 0; j < 8; ++j) a[j] = wf[OB3 + ch * 8 + j];
        const unsigned* wq = wu + OW3P + ch * 512;
#pragma unroll
        for (int r = 0; r < 64; ++r) {
#pragma unroll
            for (int j = 0; j < 8; ++j) a[j] = dot2(h2[r], wq[r * 8 + j], a[j]);
        }
        if (live) {
            uint4 v;
            v.x = pk2(fmaxf(a[0], 0.0f), fmaxf(a[1], 0.0f));
            v.y = pk2(fmaxf(a[2], 0.0f), fmaxf(a[3], 0.0f));
            v.z = pk2(fmaxf(a[4], 0.0f), fmaxf(a[5], 0.0f));
            v.w = pk2(fmaxf(a[6], 0.0f), fmaxf(a[7], 0.0f));
            feats4[(size_t)slot * 16 + ch] = v;
        }
    }
}

// ---------------- A path: per-cell max-reduce, uint4 / 4-row loads ----------------
__global__ __launch_bounds__(256)
void reduce_k(const unsigned* __restrict__ feats, const int* __restrict__ off,
              const int* __restrict__ cnt, float* __restrict__ out)
{
    __shared__ float tile[128][65];
    const int tid = threadIdx.x;
    const int w = tid >> 6, l = tid & 63;
    const int l15 = l & 15, lq = l >> 4;       // quad-row 0..3
    const int c0 = blockIdx.x * 64;
    const uint4* f4 = (const uint4*)feats;

#pragma unroll 1
    for (int cc = 0; cc < 16; ++cc) {
        int c = c0 + w * 16 + cc;
        int n = cnt[c];
        int start = off[c] - n;                // off advanced to run end by scatter
        uint4 m = {0u, 0u, 0u, 0u};
        const uint4* fp = f4 + (size_t)(start + lq) * 16 + l15;
#pragma unroll 1
        for (int p = 0; p < n; p += 4) {       // 4 points per iter, 1KB/wave/instr
            if (p + lq < n) {
                uint4 v = fp[(size_t)p * 16];
                m.x = hmax2u(m.x, v.x); m.y = hmax2u(m.y, v.y);
                m.z = hmax2u(m.z, v.z); m.w = hmax2u(m.w, v.w);
            }
        }
#pragma unroll
        for (int d = 16; d <= 32; d <<= 1) {
            m.x = hmax2u(m.x, (unsigned)__shfl_xor((int)m.x, d));
            m.y = hmax2u(m.y, (unsigned)__shfl_xor((int)m.y, d));
            m.z = hmax2u(m.z, (unsigned)__shfl_xor((int)m.z, d));
            m.w = hmax2u(m.w, (unsigned)__shfl_xor((int)m.w, d));
        }
        if (lq == 0) {                          // lanes 0..15 hold feats 8l..8l+7
            int f0 = 8 * l15, cl = w * 16 + cc;
            __half2 hx = __builtin_bit_cast(__half2, m.x);
            __half2 hy = __builtin_bit_cast(__half2, m.y);
            __half2 hz = __builtin_bit_cast(__half2, m.z);
            __half2 hw = __builtin_bit_cast(__half2, m.w);
            tile[f0 + 0][cl] = __low2float(hx); tile[f0 + 1][cl] = __high2float(hx);
            tile[f0 + 2][cl] = __low2float(hy); tile[f0 + 3][cl] = __high2float(hy);
            tile[f0 + 4][cl] = __low2float(hz); tile[f0 + 5][cl] = __high2float(hz);
            tile[f0 + 6][cl] = __low2float(hw); tile[f0 + 7][cl] = __high2float(hw);
        }
    }
    __syncthreads();
    const int b = c0 >> 14;
    const int cxy = c0 & (HW - 1);
#pragma unroll 4
    for (int k = 0; k < 32; ++k) {
        int idx = k * 256 + tid;
        int f = idx >> 6, cl = idx & 63;
        out[((size_t)(b * 128 + f)) * HW + cxy + cl] = tile[f][cl];
    }
}

// ---------------- B path: atomic fallback (correctness-only, small ws) ----------------
#define DPPMAX(A, D, S) { \
    float _pv = __int_as_float(__builtin_amdgcn_update_dpp( \
        0, __float_as_int(A), 0x110 | (D), 0xF, 0xF, false)); \
    A = (S) ? fmaxf(A, _pv) : A; }

__global__ __launch_bounds__(256, 3)
void mlp_atomic_k(const float4* __restrict__ pts, const float* __restrict__ wf,
                  const int* __restrict__ sidx, const int* __restrict__ scell,
                  const int* __restrict__ nvp, float* __restrict__ bev, int layout)
{
    const unsigned* wu = (const unsigned*)wf;
    const int tid = threadIdx.x;
    const int slot = blockIdx.x * 256 + tid;
    const int nv = nvp[0];
    if ((slot & ~63) >= nv) return;
    const int lane = tid & 63;
    const int l15 = lane & 15;
    const bool live = slot < nv;
    const int cell = live ? scell[slot] : -1;
    const int pidx = live ? sidx[slot] : 0;
    float4 p = pts[pidx];

    int c1 = __shfl_up(cell, 1), c2 = __shfl_up(cell, 2);
    int c4 = __shfl_up(cell, 4), c8 = __shfl_up(cell, 8);
    bool s1 = (l15 >= 1) && (c1 == cell);
    bool s2 = (l15 >= 2) && (c2 == cell);
    bool s4 = (l15 >= 4) && (c4 == cell);
    bool s8 = (l15 >= 8) && (c8 == cell);
    int cn = __shfl_down(cell, 1);
    bool tail = (l15 == 15) || (cn != cell);

    uv32 h1;
#pragma unroll
    for (int i = 0; i < 32; ++i) {
        const float* wa = wf + OW1 + 8 * i;
        float a = wf[OB1 + 2 * i], b = wf[OB1 + 2 * i + 1];
        a = fmaf(wa[0], p.x, a); a = fmaf(wa[1], p.y, a);
        a = fmaf(wa[2], p.z, a); a = fmaf(wa[3], p.w, a);
        b = fmaf(wa[4], p.x, b); b = fmaf(wa[5], p.y, b);
        b = fmaf(wa[6], p.z, b); b = fmaf(wa[7], p.w, b);
        h1[i] = pk2(fmaxf(a, 0.0f), fmaxf(b, 0.0f));
    }
    uv64 h2;
#pragma unroll
    for (int o0 = 0; o0 < 128; o0 += 16) {
        fv16 acc;
#pragma unroll
        for (int j = 0; j < 16; ++j) acc[j] = wf[OB2 + o0 + j];
#pragma unroll
        for (int r = 0; r < 32; ++r) {
            const unsigned* wr = wu + OW2P + r * 128 + o0;
#pragma unroll
            for (int j = 0; j < 16; ++j) acc[j] = dot2(h1[r], wr[j], acc[j]);
        }
#pragma unroll
        for (int j = 0; j < 16; j += 2)
            h2[(o0 + j) >> 1] = pk2(fmaxf(acc[j], 0.0f), fmaxf(acc[j + 1], 0.0f));
    }

    int* ob = (int*)bev;
    long base0;
    if (layout == 0) base0 = (long)cell * 128;
    else             base0 = (long)(cell >> 14) * (128 * HW) + (cell & (HW - 1));

#pragma unroll 1
    for (int ch = 0; ch < 16; ++ch) {
        fv8 a;
#pragma unroll
        for (int j = 0; j < 8; ++j) a[j] = wf[OB3 + ch * 8 + j];
        const unsigned* wq = wu + OW3P + ch * 512;
#pragma unroll
        for (int r = 0; r < 64; ++r) {
#pragma unroll
            for (int j = 0; j < 8; ++j) a[j] = dot2(h2[r], wq[r * 8 + j], a[j]);
        }
#pragma unroll
        for (int j = 0; j < 8; ++j) {
            float aj = fmaxf(a[j], 0.0f);
            DPPMAX(aj, 1, s1); DPPMAX(aj, 2, s2);
            DPPMAX(aj, 4, s4); DPPMAX(aj, 8, s8);
            a[j] = aj;
        }
        if (tail && cell >= 0) {
            if (layout == 0) {
#pragma unroll
                for (int j = 0; j < 8; ++j)
                    atomicMax(ob + base0 + ch * 8 + j, __float_as_int(a[j]));
            } else {
#pragma unroll
                for (int j = 0; j < 8; ++j)
                    atomicMax(ob + base0 + (long)(ch * 8 + j) * HW, __float_as_int(a[j]));
            }
        }
    }
}

__global__ void transpose_bev_k(const float* __restrict__ bev, float* __restrict__ out)
{
    __shared__ float tile[32][129];
    const int tid = threadIdx.x;
    const int cell0 = blockIdx.x * 32;
#pragma unroll
    for (int k = 0; k < 16; ++k) {
        int idx = k * 256 + tid;
        int c = idx >> 7, f = idx & 127;
        tile[c][f] = bev[(size_t)(cell0 + c) * 128 + f];
    }
    __syncthreads();
    const int b = cell0 >> 14;
    const int cl0 = cell0 & (HW - 1);
#pragma unroll
    for (int k = 0; k < 16; ++k) {
        int idx = k * 256 + tid;
        int f = idx >> 5, c = idx & 31;
        out[(size_t)(b * 128 + f) * HW + cl0 + c] = tile[c][f];
    }
}

extern "C" void kernel_launch(void* const* d_in, const int* in_sizes, int n_in,
                              void* d_out, int out_size, void* d_ws, size_t ws_size,
                              hipStream_t stream)
{
    const float* points = (const float*)d_in[0];
    const float* W1 = (const float*)d_in[1];  const float* b1 = (const float*)d_in[2];
    const float* g1 = (const float*)d_in[3];  const float* be1 = (const float*)d_in[4];
    const float* m1 = (const float*)d_in[5];  const float* v1 = (const float*)d_in[6];
    const float* W2 = (const float*)d_in[7];  const float* b2 = (const float*)d_in[8];
    const float* g2 = (const float*)d_in[9];  const float* be2 = (const float*)d_in[10];
    const float* m2 = (const float*)d_in[11]; const float* v2 = (const float*)d_in[12];
    const float* W3 = (const float*)d_in[13]; const float* b3 = (const float*)d_in[14];
    const float* g3 = (const float*)d_in[15]; const float* be3 = (const float*)d_in[16];
    const float* m3 = (const float*)d_in[17]; const float* v3 = (const float*)d_in[18];

    float* wsf = (float*)d_ws;
    int*   wsi = (int*)d_ws;
    const size_t need_full = ((size_t)OFEATS + (size_t)NPTS * 64) * 4;  // ~129 MB
    const size_t need_bev  = ((size_t)OBEV + BEV_ELEMS) * 4;            // ~40 MB

    fold_weights_k<<<51, 256, 0, stream>>>(
        W1, b1, g1, be1, m1, v1, W2, b2, g2, be2, m2, v2, W3, b3, g3, be3, m3, v3, wsf);

    (void)hipMemsetAsync(wsi + OCNT, 0, 65536 * sizeof(int), stream);
    cells_hist_k<<<NPTS / 256, 256, 0, stream>>>(
        (const float4*)points, wsi + OCELLS, wsi + OCNT);
    scan_k<<<1, 1024, 0, stream>>>(wsi + OCNT, wsi + OOFF, wsi + ONV);
    scatter_idx_k<<<NPTS / 256, 256, 0, stream>>>(
        wsi + OCELLS, wsi + OOFF, wsi + OSIDX, wsi + OSCELL);

    if (ws_size >= need_full) {
        uint4* feats4 = (uint4*)(wsi + OFEATS);
        mlp_feats_k<<<NPTS / 256, 256, 0, stream>>>(
            (const float4*)points, wsf, wsi + OSIDX, wsi + ONV, feats4);
        reduce_k<<<BB * HW / 64, 256, 0, stream>>>(
            (const unsigned*)feats4, wsi + OOFF, wsi + OCNT, (float*)d_out);
    } else if (ws_size >= need_bev) {
        float* bev = wsf + OBEV;
        (void)hipMemsetAsync(bev, 0, (size_t)BEV_ELEMS * sizeof(float), stream);
        mlp_atomic_k<<<NPTS / 256, 256, 0, stream>>>(
            (const float4*)points, wsf, wsi + OSIDX, wsi + OSCELL, wsi + ONV, bev, 0);
        transpose_bev_k<<<HW * BB / 32, 256, 0, stream>>>(bev, (float*)d_out);
    } else {
        (void)hipMemsetAsync(d_out, 0, (size_t)out_size * sizeof(float), stream);
        mlp_atomic_k<<<NPTS / 256, 256, 0, stream>>>(
            (const float4*)points, wsf, wsi + OSIDX, wsi + OSCELL, wsi + ONV,
            (float*)d_out, 1);
    }
}

// Round 7
// 366.695 us; speedup vs baseline: 1.5504x; 1.5141x over previous
//
#include <hip/hip_runtime.h>
#include <hip/hip_fp16.h>

#define BB 4
#define NN 120000
#define FEAT 128
#define HH 128
#define WW 128
#define NPTS (BB*NN)
#define HW (HH*WW)

// ---- ws layout (4-byte element offsets) ----
#define OW1    0         // f32[256]  [o=64][i=4]
#define OB1    256       // f32[64]
#define OW2P   320       // u32[4096] packed half2 [r=32][o=128]
#define OB2    4416      // f32[128]
#define OW3P   4544      // u32[8192] chunk layout (atomic fallback only)
#define OB3    12736     // f32[128]
#define OW3F   12864     // u32[8192] MFMA B-fragment-linear layout
#define OCNT   21056     // i32[65536]
#define OOFF   86592     // i32[65536]
#define ONV    152128    // i32[1] (padded to 64)
#define OCELLS 152192    // i32[NPTS]
#define OSIDX  632192    // i32[NPTS]
#define OSCELL 1112192   // i32[NPTS]
#define OH2    1592192   // u32[NPTS*64]: h2 fp16[slot][128], overwritten in-place by feats
#define OBEV   1592192   // fallback bev region (aliases OH2)
#define BEV_ELEMS (BB*HW*FEAT)

#if defined(__has_builtin)
#if __has_builtin(__builtin_amdgcn_fdot2)
#define HAS_FDOT2 1
#endif
#endif

typedef _Float16 hv2 __attribute__((ext_vector_type(2)));
typedef _Float16 f16x8 __attribute__((ext_vector_type(8)));
typedef float    f32x4 __attribute__((ext_vector_type(4)));
typedef float    fv16  __attribute__((ext_vector_type(16)));

__device__ __forceinline__ unsigned pk2(float a, float b) {
    __half2 h = __floats2half2_rn(a, b);
    return __builtin_bit_cast(unsigned, h);
}

__device__ __forceinline__ float dot2(unsigned a, unsigned b, float c) {
#ifdef HAS_FDOT2
    return __builtin_amdgcn_fdot2(__builtin_bit_cast(hv2, a),
                                  __builtin_bit_cast(hv2, b), c, false);
#else
    __half2 ah = __builtin_bit_cast(__half2, a), bh = __builtin_bit_cast(__half2, b);
    c = fmaf(__low2float(ah), __low2float(bh), c);
    return fmaf(__high2float(ah), __high2float(bh), c);
#endif
}

// post-ReLU fp16 (>=0) orders as unsigned halfwords
__device__ __forceinline__ unsigned hmax2u(unsigned a, unsigned b) {
    unsigned al = a & 0xFFFFu, bl = b & 0xFFFFu;
    unsigned ah = a & 0xFFFF0000u, bh = b & 0xFFFF0000u;
    unsigned lo = (al > bl) ? al : bl;
    unsigned hi = (ah > bh) ? ah : bh;
    return lo | hi;
}

// ---------------- weight folding + fp16 packing ----------------
__global__ void fold_weights_k(
    const float* __restrict__ W1, const float* __restrict__ b1,
    const float* __restrict__ g1, const float* __restrict__ be1,
    const float* __restrict__ m1, const float* __restrict__ v1,
    const float* __restrict__ W2, const float* __restrict__ b2,
    const float* __restrict__ g2, const float* __restrict__ be2,
    const float* __restrict__ m2, const float* __restrict__ v2,
    const float* __restrict__ W3, const float* __restrict__ b3,
    const float* __restrict__ g3, const float* __restrict__ be3,
    const float* __restrict__ m3, const float* __restrict__ v3,
    float* __restrict__ wf)
{
    unsigned* wu = (unsigned*)wf;
    int idx = blockIdx.x * 256 + threadIdx.x;
    const float EPSV = 1e-5f;
    if (idx < 256) {
        int o = idx >> 2;
        float s = g1[o] * rsqrtf(v1[o] + EPSV);
        wf[OW1 + idx] = W1[idx] * s;
    } else if (idx < 320) {
        int o = idx - 256;
        float s = g1[o] * rsqrtf(v1[o] + EPSV);
        wf[idx] = (b1[o] - m1[o]) * s + be1[o];
    } else if (idx < 4416) {
        int j = idx - OW2P;
        int r = j >> 7, o = j & 127;
        float s = g2[o] * rsqrtf(v2[o] + EPSV);
        wu[idx] = pk2(W2[o * 64 + 2 * r] * s, W2[o * 64 + 2 * r + 1] * s);
    } else if (idx < 4544) {
        int o = idx - OB2;
        float s = g2[o] * rsqrtf(v2[o] + EPSV);
        wf[idx] = (b2[o] - m2[o]) * s + be2[o];
    } else if (idx < 12736) {               // chunk layout (fallback path)
        int j = idx - OW3P;
        int ch = j >> 9, rem = j & 511;
        int r = rem >> 3, jj = rem & 7;
        int o = ch * 8 + jj;
        float s = g3[o] * rsqrtf(v3[o] + EPSV);
        wu[idx] = pk2(W3[o * 128 + 2 * r] * s, W3[o * 128 + 2 * r + 1] * s);
    } else if (idx < 12864) {
        int o = idx - OB3;
        float s = g3[o] * rsqrtf(v3[o] + EPSV);
        wf[idx] = (b3[o] - m3[o]) * s + be3[o];
    } else if (idx < 21056) {
        // MFMA B-fragment-linear W3: tile = nt*4+kt (nt=n/16, kt=k/32).
        // B[k][n]: lane l holds n = l&15, k = kt*32 + (l>>4)*8 + j (j=0..7).
        // u32 u within tile: l = u>>2, q = u&3 -> halves j = 2q, 2q+1.
        int u = idx - OW3F;
        int tile = u >> 8, w = u & 255;
        int l = w >> 2, q = w & 3;
        int n = (tile >> 2) * 16 + (l & 15);
        int k = (tile & 3) * 32 + ((l >> 4) << 3) + 2 * q;
        float s = g3[n] * rsqrtf(v3[n] + EPSV);
        wu[idx] = pk2(W3[n * 128 + k] * s, W3[n * 128 + k + 1] * s);
    }
}

// ---------------- sort-by-cell passes ----------------
__global__ __launch_bounds__(256)
void cells_hist_k(const float4* __restrict__ pts, int* __restrict__ cells,
                  int* __restrict__ cnt)
{
    int tid = blockIdx.x * 256 + threadIdx.x;
    float4 p = pts[tid];
    float xn = (p.x - (-50.0f)) / (50.0f - (-50.0f));
    float yn = (p.y - (-50.0f)) / (50.0f - (-50.0f));
    bool valid = (xn >= 0.0f) && (xn <= 1.0f) && (yn >= 0.0f) && (yn <= 1.0f);
    int gx = min(max((int)(xn * 127.0f), 0), 127);
    int gy = min(max((int)(yn * 127.0f), 0), 127);
    int b = tid / NN;
    int cell = valid ? (b * HW + gy * WW + gx) : -1;
    cells[tid] = cell;
    if (valid) atomicAdd(&cnt[cell], 1);
}

__global__ __launch_bounds__(1024)
void scan_k(const int* __restrict__ cnt, int* __restrict__ off, int* __restrict__ nvp)
{
    __shared__ int wsum[16];
    int t = threadIdx.x;
    int lane = t & 63, w = t >> 6;
    int base = t * 64;
    int s = 0;
#pragma unroll 8
    for (int j = 0; j < 64; ++j) s += cnt[base + j];
    int v = s;
#pragma unroll
    for (int d = 1; d < 64; d <<= 1) {
        int u = __shfl_up(v, d);
        if (lane >= d) v += u;
    }
    if (lane == 63) wsum[w] = v;
    __syncthreads();
    if (t == 0) {
        int r = 0;
#pragma unroll
        for (int k = 0; k < 16; ++k) { int x = wsum[k]; wsum[k] = r; r += x; }
        nvp[0] = r;
    }
    __syncthreads();
    int excl = (v - s) + wsum[w];
    int r = excl;
#pragma unroll 8
    for (int j = 0; j < 64; ++j) { off[base + j] = r; r += cnt[base + j]; }
}

__global__ __launch_bounds__(256)
void scatter_idx_k(const int* __restrict__ cells, int* __restrict__ off,
                   int* __restrict__ sidx, int* __restrict__ scell)
{
    int tid = blockIdx.x * 256 + threadIdx.x;
    int c = cells[tid];
    if (c >= 0) {
        int pos = atomicAdd(&off[c], 1);
        sidx[pos] = tid;
        scell[pos] = c;
    }
}

// ---------------- L1+L2: vector, h1 in LDS, chunk->global immediately ----------------
// Max live state ~30 VGPRs by construction: no cross-chunk arrays exist.
__global__ __launch_bounds__(256)
void mlp12_k(const float4* __restrict__ pts, const float* __restrict__ wf,
             const int* __restrict__ sidx, const int* __restrict__ nvp,
             uint4* __restrict__ h2g4)
{
    __shared__ unsigned h1s[32 * 256];
    const unsigned* wu = (const unsigned*)wf;
    const int tid = threadIdx.x;
    const int slot = blockIdx.x * 256 + tid;
    const int nv = nvp[0];
    if ((slot & ~63) >= nv) return;
    const bool live = slot < nv;
    const int pidx = live ? sidx[slot] : 0;
    float4 p = pts[pidx];

    // layer 1: 4 -> 64 -> LDS thread-column (conflict-free, no barrier needed)
#pragma unroll
    for (int i = 0; i < 32; ++i) {
        const float* wa = wf + OW1 + 8 * i;
        float a = wf[OB1 + 2 * i], b = wf[OB1 + 2 * i + 1];
        a = fmaf(wa[0], p.x, a); a = fmaf(wa[1], p.y, a);
        a = fmaf(wa[2], p.z, a); a = fmaf(wa[3], p.w, a);
        b = fmaf(wa[4], p.x, b); b = fmaf(wa[5], p.y, b);
        b = fmaf(wa[6], p.z, b); b = fmaf(wa[7], p.w, b);
        h1s[i * 256 + tid] = pk2(fmaxf(a, 0.0f), fmaxf(b, 0.0f));
    }

    // layer 2: 64 -> 128, 16 outputs at a time, store chunk and forget it
#pragma unroll 1
    for (int o0 = 0; o0 < 128; o0 += 16) {
        fv16 acc;
#pragma unroll
        for (int j = 0; j < 16; ++j) acc[j] = wf[OB2 + o0 + j];
#pragma unroll
        for (int r = 0; r < 32; ++r) {
            unsigned h1r = h1s[r * 256 + tid];
            const unsigned* wr = wu + OW2P + r * 128 + o0;
#pragma unroll
            for (int j = 0; j < 16; ++j) acc[j] = dot2(h1r, wr[j], acc[j]);
        }
        uint4 v0, v1;
        v0.x = pk2(fmaxf(acc[0], 0.f), fmaxf(acc[1], 0.f));
        v0.y = pk2(fmaxf(acc[2], 0.f), fmaxf(acc[3], 0.f));
        v0.z = pk2(fmaxf(acc[4], 0.f), fmaxf(acc[5], 0.f));
        v0.w = pk2(fmaxf(acc[6], 0.f), fmaxf(acc[7], 0.f));
        v1.x = pk2(fmaxf(acc[8], 0.f), fmaxf(acc[9], 0.f));
        v1.y = pk2(fmaxf(acc[10], 0.f), fmaxf(acc[11], 0.f));
        v1.z = pk2(fmaxf(acc[12], 0.f), fmaxf(acc[13], 0.f));
        v1.w = pk2(fmaxf(acc[14], 0.f), fmaxf(acc[15], 0.f));
        if (!live) { v0.x=v0.y=v0.z=v0.w=0u; v1 = v0; }
        h2g4[(size_t)slot * 16 + (o0 >> 3) + 0] = v0;
        h2g4[(size_t)slot * 16 + (o0 >> 3) + 1] = v1;
    }
}

// ---------------- L3 via MFMA 16x16x32 f16; feats overwrite h2 in place ----------------
// A[m=lane&15][k=quad*8+j] from h2[slot][k]; B frag-linear from OW3F;
// C/D: col=lane&15 (feature), row=quad*4+reg (point).
__global__ __launch_bounds__(256)
void mfma_l3_k(const float* __restrict__ wf, const int* __restrict__ nvp,
               uint4* __restrict__ h2g4)
{
    __shared__ __align__(16) _Float16 stage[4][16 * 128];
    const unsigned* wu = (const unsigned*)wf;
    const uint4* bfrag4 = (const uint4*)(wu + OW3F);
    const int tid = threadIdx.x, wv = tid >> 6, l = tid & 63;
    const int nv = nvp[0];
    const int M0 = (blockIdx.x * 4 + wv) * 16;
    if (M0 >= nv) return;                      // wave-uniform
    const int l15 = l & 15, q = l >> 4;

    // all A-fragments up front (also guarantees reads precede in-place stores)
    uint4 a_raw[4];
#pragma unroll
    for (int kt = 0; kt < 4; ++kt)
        a_raw[kt] = h2g4[(size_t)(M0 + l15) * 16 + kt * 4 + q];

#pragma unroll 1
    for (int nt = 0; nt < 8; ++nt) {
        float bias = wf[OB3 + nt * 16 + l15];
        f32x4 acc = {0.f, 0.f, 0.f, 0.f};
#pragma unroll
        for (int kt = 0; kt < 4; ++kt) {
            uint4 braw = bfrag4[(nt * 4 + kt) * 64 + l];
            acc = __builtin_amdgcn_mfma_f32_16x16x32_f16(
                __builtin_bit_cast(f16x8, a_raw[kt]),
                __builtin_bit_cast(f16x8, braw), acc, 0, 0, 0);
        }
#pragma unroll
        for (int r = 0; r < 4; ++r) {
            float v = fmaxf(acc[r] + bias, 0.0f);
            stage[wv][(q * 4 + r) * 128 + nt * 16 + l15] = (_Float16)v;
        }
    }
    // linearize: lane covers a quarter-row; 4KB contiguous per wave store
    const uint4* sp = (const uint4*)(&stage[wv][0]);
#pragma unroll
    for (int i = 0; i < 4; ++i) {
        uint4 vv = sp[(l >> 2) * 16 + (l & 3) * 4 + i];
        h2g4[(size_t)(M0 + (l >> 2)) * 16 + (l & 3) * 4 + i] = vv;
    }
}

// ---------------- per-cell max-reduce, uint4 / 4-row loads ----------------
__global__ __launch_bounds__(256)
void reduce_k(const unsigned* __restrict__ feats, const int* __restrict__ off,
              const int* __restrict__ cnt, float* __restrict__ out)
{
    __shared__ float tile[128][65];
    const int tid = threadIdx.x;
    const int w = tid >> 6, l = tid & 63;
    const int l15 = l & 15, lq = l >> 4;
    const int c0 = blockIdx.x * 64;
    const uint4* f4 = (const uint4*)feats;

#pragma unroll 1
    for (int cc = 0; cc < 16; ++cc) {
        int c = c0 + w * 16 + cc;
        int n = cnt[c];
        int start = off[c] - n;                // off advanced to run end by scatter
        uint4 m = {0u, 0u, 0u, 0u};
        const uint4* fp = f4 + (size_t)(start + lq) * 16 + l15;
#pragma unroll 1
        for (int p = 0; p < n; p += 4) {
            if (p + lq < n) {
                uint4 v = fp[(size_t)p * 16];
                m.x = hmax2u(m.x, v.x); m.y = hmax2u(m.y, v.y);
                m.z = hmax2u(m.z, v.z); m.w = hmax2u(m.w, v.w);
            }
        }
#pragma unroll
        for (int d = 16; d <= 32; d <<= 1) {
            m.x = hmax2u(m.x, (unsigned)__shfl_xor((int)m.x, d));
            m.y = hmax2u(m.y, (unsigned)__shfl_xor((int)m.y, d));
            m.z = hmax2u(m.z, (unsigned)__shfl_xor((int)m.z, d));
            m.w = hmax2u(m.w, (unsigned)__shfl_xor((int)m.w, d));
        }
        if (lq == 0) {
            int f0 = 8 * l15, cl = w * 16 + cc;
            __half2 hx = __builtin_bit_cast(__half2, m.x);
            __half2 hy = __builtin_bit_cast(__half2, m.y);
            __half2 hz = __builtin_bit_cast(__half2, m.z);
            __half2 hw = __builtin_bit_cast(__half2, m.w);
            tile[f0 + 0][cl] = __low2float(hx); tile[f0 + 1][cl] = __high2float(hx);
            tile[f0 + 2][cl] = __low2float(hy); tile[f0 + 3][cl] = __high2float(hy);
            tile[f0 + 4][cl] = __low2float(hz); tile[f0 + 5][cl] = __high2float(hz);
            tile[f0 + 6][cl] = __low2float(hw); tile[f0 + 7][cl] = __high2float(hw);
        }
    }
    __syncthreads();
    const int b = c0 >> 14;
    const int cxy = c0 & (HW - 1);
#pragma unroll 4
    for (int k = 0; k < 32; ++k) {
        int idx = k * 256 + tid;
        int f = idx >> 6, cl = idx & 63;
        out[((size_t)(b * 128 + f)) * HW + cxy + cl] = tile[f][cl];
    }
}

// ---------------- small-ws fallback: sorted+run-merged atomics ----------------
#define DPPMAX(A, D, S) { \
    float _pv = __int_as_float(__builtin_amdgcn_update_dpp( \
        0, __float_as_int(A), 0x110 | (D), 0xF, 0xF, false)); \
    A = (S) ? fmaxf(A, _pv) : A; }

__global__ __launch_bounds__(256)
void mlp_atomic_k(const float4* __restrict__ pts, const float* __restrict__ wf,
                  const int* __restrict__ sidx, const int* __restrict__ scell,
                  const int* __restrict__ nvp, float* __restrict__ bev, int layout)
{
    __shared__ unsigned h1s[32 * 256];
    __shared__ unsigned h2s[64 * 256];
    const unsigned* wu = (const unsigned*)wf;
    const int tid = threadIdx.x;
    const int slot = blockIdx.x * 256 + tid;
    const int nv = nvp[0];
    if ((slot & ~63) >= nv) return;
    const int lane = tid & 63;
    const int l15 = lane & 15;
    const bool live = slot < nv;
    const int cell = live ? scell[slot] : -1;
    const int pidx = live ? sidx[slot] : 0;
    float4 p = pts[pidx];

    int c1 = __shfl_up(cell, 1), c2 = __shfl_up(cell, 2);
    int c4 = __shfl_up(cell, 4), c8 = __shfl_up(cell, 8);
    bool s1 = (l15 >= 1) && (c1 == cell);
    bool s2 = (l15 >= 2) && (c2 == cell);
    bool s4 = (l15 >= 4) && (c4 == cell);
    bool s8 = (l15 >= 8) && (c8 == cell);
    int cn = __shfl_down(cell, 1);
    bool tail = (l15 == 15) || (cn != cell);

#pragma unroll
    for (int i = 0; i < 32; ++i) {
        const float* wa = wf + OW1 + 8 * i;
        float a = wf[OB1 + 2 * i], b = wf[OB1 + 2 * i + 1];
        a = fmaf(wa[0], p.x, a); a = fmaf(wa[1], p.y, a);
        a = fmaf(wa[2], p.z, a); a = fmaf(wa[3], p.w, a);
        b = fmaf(wa[4], p.x, b); b = fmaf(wa[5], p.y, b);
        b = fmaf(wa[6], p.z, b); b = fmaf(wa[7], p.w, b);
        h1s[i * 256 + tid] = pk2(fmaxf(a, 0.0f), fmaxf(b, 0.0f));
    }
#pragma unroll 1
    for (int o0 = 0; o0 < 128; o0 += 16) {
        fv16 acc;
#pragma unroll
        for (int j = 0; j < 16; ++j) acc[j] = wf[OB2 + o0 + j];
#pragma unroll
        for (int r = 0; r < 32; ++r) {
            unsigned h1r = h1s[r * 256 + tid];
            const unsigned* wr = wu + OW2P + r * 128 + o0;
#pragma unroll
            for (int j = 0; j < 16; ++j) acc[j] = dot2(h1r, wr[j], acc[j]);
        }
#pragma unroll
        for (int j = 0; j < 16; j += 2)
            h2s[((o0 + j) >> 1) * 256 + tid] =
                pk2(fmaxf(acc[j], 0.f), fmaxf(acc[j + 1], 0.f));
    }

    int* ob = (int*)bev;
    long base0;
    if (layout == 0) base0 = (long)cell * 128;
    else             base0 = (long)(cell >> 14) * (128 * HW) + (cell & (HW - 1));

#pragma unroll 1
    for (int ch = 0; ch < 16; ++ch) {
        float a0=wf[OB3+ch*8+0], a1=wf[OB3+ch*8+1], a2=wf[OB3+ch*8+2], a3=wf[OB3+ch*8+3];
        float a4=wf[OB3+ch*8+4], a5=wf[OB3+ch*8+5], a6=wf[OB3+ch*8+6], a7=wf[OB3+ch*8+7];
        const unsigned* wq = wu + OW3P + ch * 512;
#pragma unroll
        for (int r = 0; r < 64; ++r) {
            unsigned h2r = h2s[r * 256 + tid];
            a0 = dot2(h2r, wq[r*8+0], a0); a1 = dot2(h2r, wq[r*8+1], a1);
            a2 = dot2(h2r, wq[r*8+2], a2); a3 = dot2(h2r, wq[r*8+3], a3);
            a4 = dot2(h2r, wq[r*8+4], a4); a5 = dot2(h2r, wq[r*8+5], a5);
            a6 = dot2(h2r, wq[r*8+6], a6); a7 = dot2(h2r, wq[r*8+7], a7);
        }
        float av[8] = {a0,a1,a2,a3,a4,a5,a6,a7};
#pragma unroll
        for (int j = 0; j < 8; ++j) {
            float aj = fmaxf(av[j], 0.0f);
            DPPMAX(aj, 1, s1); DPPMAX(aj, 2, s2);
            DPPMAX(aj, 4, s4); DPPMAX(aj, 8, s8);
            av[j] = aj;
        }
        if (tail && cell >= 0) {
            if (layout == 0) {
#pragma unroll
                for (int j = 0; j < 8; ++j)
                    atomicMax(ob + base0 + ch * 8 + j, __float_as_int(av[j]));
            } else {
#pragma unroll
                for (int j = 0; j < 8; ++j)
                    atomicMax(ob + base0 + (long)(ch * 8 + j) * HW, __float_as_int(av[j]));
            }
        }
    }
}

__global__ void transpose_bev_k(const float* __restrict__ bev, float* __restrict__ out)
{
    __shared__ float tile[32][129];
    const int tid = threadIdx.x;
    const int cell0 = blockIdx.x * 32;
#pragma unroll
    for (int k = 0; k < 16; ++k) {
        int idx = k * 256 + tid;
        int c = idx >> 7, f = idx & 127;
        tile[c][f] = bev[(size_t)(cell0 + c) * 128 + f];
    }
    __syncthreads();
    const int b = cell0 >> 14;
    const int cl0 = cell0 & (HW - 1);
#pragma unroll
    for (int k = 0; k < 16; ++k) {
        int idx = k * 256 + tid;
        int f = idx >> 5, c = idx & 31;
        out[(size_t)(b * 128 + f) * HW + cl0 + c] = tile[c][f];
    }
}

extern "C" void kernel_launch(void* const* d_in, const int* in_sizes, int n_in,
                              void* d_out, int out_size, void* d_ws, size_t ws_size,
                              hipStream_t stream)
{
    const float* points = (const float*)d_in[0];
    const float* W1 = (const float*)d_in[1];  const float* b1 = (const float*)d_in[2];
    const float* g1 = (const float*)d_in[3];  const float* be1 = (const float*)d_in[4];
    const float* m1 = (const float*)d_in[5];  const float* v1 = (const float*)d_in[6];
    const float* W2 = (const float*)d_in[7];  const float* b2 = (const float*)d_in[8];
    const float* g2 = (const float*)d_in[9];  const float* be2 = (const float*)d_in[10];
    const float* m2 = (const float*)d_in[11]; const float* v2 = (const float*)d_in[12];
    const float* W3 = (const float*)d_in[13]; const float* b3 = (const float*)d_in[14];
    const float* g3 = (const float*)d_in[15]; const float* be3 = (const float*)d_in[16];
    const float* m3 = (const float*)d_in[17]; const float* v3 = (const float*)d_in[18];

    float* wsf = (float*)d_ws;
    int*   wsi = (int*)d_ws;
    const size_t need_full = ((size_t)OH2 + (size_t)NPTS * 64) * 4;   // ~129.3 MB
    const size_t need_bev  = ((size_t)OBEV + BEV_ELEMS) * 4;          // ~40 MB

    fold_weights_k<<<83, 256, 0, stream>>>(
        W1, b1, g1, be1, m1, v1, W2, b2, g2, be2, m2, v2, W3, b3, g3, be3, m3, v3, wsf);

    (void)hipMemsetAsync(wsi + OCNT, 0, 65536 * sizeof(int), stream);
    cells_hist_k<<<NPTS / 256, 256, 0, stream>>>(
        (const float4*)points, wsi + OCELLS, wsi + OCNT);
    scan_k<<<1, 1024, 0, stream>>>(wsi + OCNT, wsi + OOFF, wsi + ONV);
    scatter_idx_k<<<NPTS / 256, 256, 0, stream>>>(
        wsi + OCELLS, wsi + OOFF, wsi + OSIDX, wsi + OSCELL);

    if (ws_size >= need_full) {
        uint4* h2g4 = (uint4*)(wsi + OH2);
        mlp12_k<<<NPTS / 256, 256, 0, stream>>>(
            (const float4*)points, wsf, wsi + OSIDX, wsi + ONV, h2g4);
        mfma_l3_k<<<NPTS / 64, 256, 0, stream>>>(wsf, wsi + ONV, h2g4);
        reduce_k<<<BB * HW / 64, 256, 0, stream>>>(
            (const unsigned*)h2g4, wsi + OOFF, wsi + OCNT, (float*)d_out);
    } else if (ws_size >= need_bev) {
        float* bev = wsf + OBEV;
        (void)hipMemsetAsync(bev, 0, (size_t)BEV_ELEMS * sizeof(float), stream);
        mlp_atomic_k<<<NPTS / 256, 256, 0, stream>>>(
            (const float4*)points, wsf, wsi + OSIDX, wsi + OSCELL, wsi + ONV, bev, 0);
        transpose_bev_k<<<HW * BB / 32, 256, 0, stream>>>(bev, (float*)d_out);
    } else {
        (void)hipMemsetAsync(d_out, 0, (size_t)out_size * sizeof(float), stream);
        mlp_atomic_k<<<NPTS / 256, 256, 0, stream>>>(
            (const float4*)points, wsf, wsi + OSIDX, wsi + OSCELL, wsi + ONV,
            (float*)d_out, 1);
    }
}

// Round 8
// 289.282 us; speedup vs baseline: 1.9653x; 1.2676x over previous
//
#include <hip/hip_runtime.h>
#include <hip/hip_fp16.h>

#define BB 4
#define NN 120000
#define FEAT 128
#define HH 128
#define WW 128
#define NPTS (BB*NN)
#define HW (HH*WW)

// ---- ws layout (4-byte element offsets) ----
#define OW1    0         // f32[256]  [o=64][i=4]
#define OB1    256       // f32[64]
#define OW2P   320       // u32[4096] packed half2 [r=32][o=128] (fallback)
#define OB2    4416      // f32[128]
#define OW3P   4544      // u32[8192] chunk layout (fallback)
#define OB3    12736     // f32[128]
#define OW3F   12864     // u32[8192] MFMA B-frag-linear W3 (verified r7)
#define OW2F   21056     // u32[4096] MFMA B-frag-linear W2 (new)
#define OCNT   25152     // i32[65536]
#define OOFF   90688     // i32[65536]
#define ONV    156224    // i32[1] (padded to 64)
#define OCELLS 156288    // i32[NPTS]
#define OSIDX  636288    // i32[NPTS]
#define OSCELL 1116288   // i32[NPTS]
#define OFEATS 1596288   // u32[NPTS*64] fp16 feats [slot][128]
#define OBEV   1596288   // fallback bev region (aliases OFEATS)
#define BEV_ELEMS (BB*HW*FEAT)

#if defined(__has_builtin)
#if __has_builtin(__builtin_amdgcn_fdot2)
#define HAS_FDOT2 1
#endif
#endif

typedef _Float16 hv2 __attribute__((ext_vector_type(2)));
typedef _Float16 f16x8 __attribute__((ext_vector_type(8)));
typedef float    f32x4 __attribute__((ext_vector_type(4)));
typedef float    fv16  __attribute__((ext_vector_type(16)));

__device__ __forceinline__ unsigned pk2(float a, float b) {
    __half2 h = __floats2half2_rn(a, b);
    return __builtin_bit_cast(unsigned, h);
}

__device__ __forceinline__ float dot2(unsigned a, unsigned b, float c) {
#ifdef HAS_FDOT2
    return __builtin_amdgcn_fdot2(__builtin_bit_cast(hv2, a),
                                  __builtin_bit_cast(hv2, b), c, false);
#else
    __half2 ah = __builtin_bit_cast(__half2, a), bh = __builtin_bit_cast(__half2, b);
    c = fmaf(__low2float(ah), __low2float(bh), c);
    return fmaf(__high2float(ah), __high2float(bh), c);
#endif
}

// post-ReLU fp16 (>=0) orders as unsigned halfwords
__device__ __forceinline__ unsigned hmax2u(unsigned a, unsigned b) {
    unsigned al = a & 0xFFFFu, bl = b & 0xFFFFu;
    unsigned ah = a & 0xFFFF0000u, bh = b & 0xFFFF0000u;
    unsigned lo = (al > bl) ? al : bl;
    unsigned hi = (ah > bh) ? ah : bh;
    return lo | hi;
}

// ---------------- weight folding + fp16 packing ----------------
__global__ void fold_weights_k(
    const float* __restrict__ W1, const float* __restrict__ b1,
    const float* __restrict__ g1, const float* __restrict__ be1,
    const float* __restrict__ m1, const float* __restrict__ v1,
    const float* __restrict__ W2, const float* __restrict__ b2,
    const float* __restrict__ g2, const float* __restrict__ be2,
    const float* __restrict__ m2, const float* __restrict__ v2,
    const float* __restrict__ W3, const float* __restrict__ b3,
    const float* __restrict__ g3, const float* __restrict__ be3,
    const float* __restrict__ m3, const float* __restrict__ v3,
    float* __restrict__ wf)
{
    unsigned* wu = (unsigned*)wf;
    int idx = blockIdx.x * 256 + threadIdx.x;
    const float EPSV = 1e-5f;
    if (idx < 256) {
        int o = idx >> 2;
        float s = g1[o] * rsqrtf(v1[o] + EPSV);
        wf[OW1 + idx] = W1[idx] * s;
    } else if (idx < 320) {
        int o = idx - 256;
        float s = g1[o] * rsqrtf(v1[o] + EPSV);
        wf[idx] = (b1[o] - m1[o]) * s + be1[o];
    } else if (idx < 4416) {
        int j = idx - OW2P;
        int r = j >> 7, o = j & 127;
        float s = g2[o] * rsqrtf(v2[o] + EPSV);
        wu[idx] = pk2(W2[o * 64 + 2 * r] * s, W2[o * 64 + 2 * r + 1] * s);
    } else if (idx < 4544) {
        int o = idx - OB2;
        float s = g2[o] * rsqrtf(v2[o] + EPSV);
        wf[idx] = (b2[o] - m2[o]) * s + be2[o];
    } else if (idx < 12736) {               // chunk layout (fallback path)
        int j = idx - OW3P;
        int ch = j >> 9, rem = j & 511;
        int r = rem >> 3, jj = rem & 7;
        int o = ch * 8 + jj;
        float s = g3[o] * rsqrtf(v3[o] + EPSV);
        wu[idx] = pk2(W3[o * 128 + 2 * r] * s, W3[o * 128 + 2 * r + 1] * s);
    } else if (idx < 12864) {
        int o = idx - OB3;
        float s = g3[o] * rsqrtf(v3[o] + EPSV);
        wf[idx] = (b3[o] - m3[o]) * s + be3[o];
    } else if (idx < 21056) {
        // W3 B-frag-linear: tile = nt*4+kt; lane l: n=(tile>>2)*16+(l&15),
        // k=(tile&3)*32+(l>>4)*8+j. u32 u: l=u>>2, q=u&3 -> j=2q,2q+1.
        int u = idx - OW3F;
        int tile = u >> 8, w = u & 255;
        int l = w >> 2, q = w & 3;
        int n = (tile >> 2) * 16 + (l & 15);
        int k = (tile & 3) * 32 + ((l >> 4) << 3) + 2 * q;
        float s = g3[n] * rsqrtf(v3[n] + EPSV);
        wu[idx] = pk2(W3[n * 128 + k] * s, W3[n * 128 + k + 1] * s);
    } else if (idx < 25152) {
        // W2 B-frag-linear: tile = nt*2+kt (K=64 -> 2 k-tiles)
        int u = idx - OW2F;
        int tile = u >> 8, w = u & 255;
        int l = w >> 2, q = w & 3;
        int n = (tile >> 1) * 16 + (l & 15);
        int k = (tile & 1) * 32 + ((l >> 4) << 3) + 2 * q;
        float s = g2[n] * rsqrtf(v2[n] + EPSV);
        wu[idx] = pk2(W2[n * 64 + k] * s, W2[n * 64 + k + 1] * s);
    }
}

// ---------------- sort-by-cell passes ----------------
__global__ __launch_bounds__(256)
void cells_hist_k(const float4* __restrict__ pts, int* __restrict__ cells,
                  int* __restrict__ cnt)
{
    int tid = blockIdx.x * 256 + threadIdx.x;
    float4 p = pts[tid];
    float xn = (p.x - (-50.0f)) / (50.0f - (-50.0f));
    float yn = (p.y - (-50.0f)) / (50.0f - (-50.0f));
    bool valid = (xn >= 0.0f) && (xn <= 1.0f) && (yn >= 0.0f) && (yn <= 1.0f);
    int gx = min(max((int)(xn * 127.0f), 0), 127);
    int gy = min(max((int)(yn * 127.0f), 0), 127);
    int b = tid / NN;
    int cell = valid ? (b * HW + gy * WW + gx) : -1;
    cells[tid] = cell;
    if (valid) atomicAdd(&cnt[cell], 1);
}

__global__ __launch_bounds__(1024)
void scan_k(const int* __restrict__ cnt, int* __restrict__ off, int* __restrict__ nvp)
{
    __shared__ int wsum[16];
    int t = threadIdx.x;
    int lane = t & 63, w = t >> 6;
    int base = t * 64;
    int s = 0;
#pragma unroll 8
    for (int j = 0; j < 64; ++j) s += cnt[base + j];
    int v = s;
#pragma unroll
    for (int d = 1; d < 64; d <<= 1) {
        int u = __shfl_up(v, d);
        if (lane >= d) v += u;
    }
    if (lane == 63) wsum[w] = v;
    __syncthreads();
    if (t == 0) {
        int r = 0;
#pragma unroll
        for (int k = 0; k < 16; ++k) { int x = wsum[k]; wsum[k] = r; r += x; }
        nvp[0] = r;
    }
    __syncthreads();
    int excl = (v - s) + wsum[w];
    int r = excl;
#pragma unroll 8
    for (int j = 0; j < 64; ++j) { off[base + j] = r; r += cnt[base + j]; }
}

__global__ __launch_bounds__(256)
void scatter_idx_k(const int* __restrict__ cells, int* __restrict__ off,
                   int* __restrict__ sidx, int* __restrict__ scell)
{
    int tid = blockIdx.x * 256 + threadIdx.x;
    int c = cells[tid];
    if (c >= 0) {
        int pos = atomicAdd(&off[c], 1);
        sidx[pos] = tid;
        scell[pos] = c;
    }
}

// ---------------- fused L1(VALU)+L2(MFMA)+L3(MFMA), h2 stays in LDS ----------------
// Wave = 16 points. All LDS traffic is intra-wave (in-order per wave, no barriers).
// A-frag: A[m=lane&15][k=quad*8+j]; C/D: col=lane&15, row=quad*4+reg (verified r7).
__global__ __launch_bounds__(256)
void fused_mlp_k(const float4* __restrict__ pts, const float* __restrict__ wf,
                 const int* __restrict__ sidx, const int* __restrict__ nvp,
                 uint4* __restrict__ feats4)
{
    __shared__ __align__(16) _Float16 h1t[4][16 * 72];    // stride 72 breaks bank align
    __shared__ __align__(16) _Float16 h2t[4][16 * 136];   // stride 136
    __shared__ __align__(16) _Float16 stg[4][16 * 136];
    const unsigned* wu = (const unsigned*)wf;
    const uint4* bf2 = (const uint4*)(wu + OW2F);
    const uint4* bf3 = (const uint4*)(wu + OW3F);
    const int tid = threadIdx.x, wv = tid >> 6, l = tid & 63;
    const int nv = nvp[0];
    const int M0 = (blockIdx.x * 4 + wv) * 16;
    if (M0 >= nv) return;                       // wave-uniform
    const int l15 = l & 15, q = l >> 4;

    const int slot = M0 + l15;
    const int pidx = (slot < nv) ? sidx[slot] : 0;
    float4 p = pts[pidx];

    // ---- layer 1: lane (q,l15) computes h1 outs o = q*16..q*16+15 of point l15
    unsigned r0[8];
#pragma unroll
    for (int t = 0; t < 8; ++t) {
        int o = q * 16 + 2 * t;
        const float* wa = wf + OW1 + o * 4;
        float a = wf[OB1 + o], b = wf[OB1 + o + 1];
        a = fmaf(wa[0], p.x, a); a = fmaf(wa[1], p.y, a);
        a = fmaf(wa[2], p.z, a); a = fmaf(wa[3], p.w, a);
        b = fmaf(wa[4], p.x, b); b = fmaf(wa[5], p.y, b);
        b = fmaf(wa[6], p.z, b); b = fmaf(wa[7], p.w, b);
        r0[t] = pk2(fmaxf(a, 0.f), fmaxf(b, 0.f));
    }
    {
        uint4* dst = (uint4*)&h1t[wv][l15 * 72 + q * 16];
        uint4 v0; v0.x = r0[0]; v0.y = r0[1]; v0.z = r0[2]; v0.w = r0[3];
        uint4 v1; v1.x = r0[4]; v1.y = r0[5]; v1.z = r0[6]; v1.w = r0[7];
        dst[0] = v0; dst[1] = v1;
    }

    // ---- A2 fragments (intra-wave RAW on h1t)
    uint4 a2[2];
#pragma unroll
    for (int kt = 0; kt < 2; ++kt)
        a2[kt] = *(const uint4*)&h1t[wv][l15 * 72 + kt * 32 + q * 8];

    // ---- L2: 8 n-tiles x 2 k-tiles -> h2 tile in LDS
#pragma unroll 1
    for (int nt = 0; nt < 8; ++nt) {
        f32x4 acc = {0.f, 0.f, 0.f, 0.f};
        acc = __builtin_amdgcn_mfma_f32_16x16x32_f16(
            __builtin_bit_cast(f16x8, a2[0]),
            __builtin_bit_cast(f16x8, bf2[(nt * 2 + 0) * 64 + l]), acc, 0, 0, 0);
        acc = __builtin_amdgcn_mfma_f32_16x16x32_f16(
            __builtin_bit_cast(f16x8, a2[1]),
            __builtin_bit_cast(f16x8, bf2[(nt * 2 + 1) * 64 + l]), acc, 0, 0, 0);
        float bias = wf[OB2 + nt * 16 + l15];
#pragma unroll
        for (int rr = 0; rr < 4; ++rr)
            h2t[wv][(q * 4 + rr) * 136 + nt * 16 + l15] =
                (_Float16)fmaxf(acc[rr] + bias, 0.f);
    }

    // ---- A3 fragments (intra-wave RAW on h2t)
    uint4 a3[4];
#pragma unroll
    for (int kt = 0; kt < 4; ++kt)
        a3[kt] = *(const uint4*)&h2t[wv][l15 * 136 + kt * 32 + q * 8];

    // ---- L3: 8 n-tiles x 4 k-tiles -> stage
#pragma unroll 1
    for (int nt = 0; nt < 8; ++nt) {
        f32x4 acc = {0.f, 0.f, 0.f, 0.f};
#pragma unroll
        for (int kt = 0; kt < 4; ++kt)
            acc = __builtin_amdgcn_mfma_f32_16x16x32_f16(
                __builtin_bit_cast(f16x8, a3[kt]),
                __builtin_bit_cast(f16x8, bf3[(nt * 4 + kt) * 64 + l]), acc, 0, 0, 0);
        float bias = wf[OB3 + nt * 16 + l15];
#pragma unroll
        for (int rr = 0; rr < 4; ++rr)
            stg[wv][(q * 4 + rr) * 136 + nt * 16 + l15] =
                (_Float16)fmaxf(acc[rr] + bias, 0.f);
    }

    // ---- coalesced writeout: 4KB contiguous per wave
    const int pt = l >> 2, part = l & 3;
#pragma unroll
    for (int i = 0; i < 4; ++i) {
        uint4 vv = *(const uint4*)&stg[wv][pt * 136 + (part * 4 + i) * 8];
        feats4[(size_t)(M0 + pt) * 16 + part * 4 + i] = vv;
    }
}

// ---------------- per-cell max-reduce, uint4 / 4-row loads ----------------
__global__ __launch_bounds__(256)
void reduce_k(const unsigned* __restrict__ feats, const int* __restrict__ off,
              const int* __restrict__ cnt, float* __restrict__ out)
{
    __shared__ float tile[128][65];
    const int tid = threadIdx.x;
    const int w = tid >> 6, l = tid & 63;
    const int l15 = l & 15, lq = l >> 4;
    const int c0 = blockIdx.x * 64;
    const uint4* f4 = (const uint4*)feats;

#pragma unroll 1
    for (int cc = 0; cc < 16; ++cc) {
        int c = c0 + w * 16 + cc;
        int n = cnt[c];
        int start = off[c] - n;                // off advanced to run end by scatter
        uint4 m = {0u, 0u, 0u, 0u};
        const uint4* fp = f4 + (size_t)(start + lq) * 16 + l15;
#pragma unroll 1
        for (int p = 0; p < n; p += 4) {
            if (p + lq < n) {
                uint4 v = fp[(size_t)p * 16];
                m.x = hmax2u(m.x, v.x); m.y = hmax2u(m.y, v.y);
                m.z = hmax2u(m.z, v.z); m.w = hmax2u(m.w, v.w);
            }
        }
#pragma unroll
        for (int d = 16; d <= 32; d <<= 1) {
            m.x = hmax2u(m.x, (unsigned)__shfl_xor((int)m.x, d));
            m.y = hmax2u(m.y, (unsigned)__shfl_xor((int)m.y, d));
            m.z = hmax2u(m.z, (unsigned)__shfl_xor((int)m.z, d));
            m.w = hmax2u(m.w, (unsigned)__shfl_xor((int)m.w, d));
        }
        if (lq == 0) {
            int f0 = 8 * l15, cl = w * 16 + cc;
            __half2 hx = __builtin_bit_cast(__half2, m.x);
            __half2 hy = __builtin_bit_cast(__half2, m.y);
            __half2 hz = __builtin_bit_cast(__half2, m.z);
            __half2 hw = __builtin_bit_cast(__half2, m.w);
            tile[f0 + 0][cl] = __low2float(hx); tile[f0 + 1][cl] = __high2float(hx);
            tile[f0 + 2][cl] = __low2float(hy); tile[f0 + 3][cl] = __high2float(hy);
            tile[f0 + 4][cl] = __low2float(hz); tile[f0 + 5][cl] = __high2float(hz);
            tile[f0 + 6][cl] = __low2float(hw); tile[f0 + 7][cl] = __high2float(hw);
        }
    }
    __syncthreads();
    const int b = c0 >> 14;
    const int cxy = c0 & (HW - 1);
#pragma unroll 4
    for (int k = 0; k < 32; ++k) {
        int idx = k * 256 + tid;
        int f = idx >> 6, cl = idx & 63;
        out[((size_t)(b * 128 + f)) * HW + cxy + cl] = tile[f][cl];
    }
}

// ---------------- small-ws fallback: sorted+run-merged atomics ----------------
#define DPPMAX(A, D, S) { \
    float _pv = __int_as_float(__builtin_amdgcn_update_dpp( \
        0, __float_as_int(A), 0x110 | (D), 0xF, 0xF, false)); \
    A = (S) ? fmaxf(A, _pv) : A; }

__global__ __launch_bounds__(256)
void mlp_atomic_k(const float4* __restrict__ pts, const float* __restrict__ wf,
                  const int* __restrict__ sidx, const int* __restrict__ scell,
                  const int* __restrict__ nvp, float* __restrict__ bev, int layout)
{
    __shared__ unsigned h1s[32 * 256];
    __shared__ unsigned h2s[64 * 256];
    const unsigned* wu = (const unsigned*)wf;
    const int tid = threadIdx.x;
    const int slot = blockIdx.x * 256 + tid;
    const int nv = nvp[0];
    if ((slot & ~63) >= nv) return;
    const int lane = tid & 63;
    const int l15 = lane & 15;
    const bool live = slot < nv;
    const int cell = live ? scell[slot] : -1;
    const int pidx = live ? sidx[slot] : 0;
    float4 p = pts[pidx];

    int c1 = __shfl_up(cell, 1), c2 = __shfl_up(cell, 2);
    int c4 = __shfl_up(cell, 4), c8 = __shfl_up(cell, 8);
    bool s1 = (l15 >= 1) && (c1 == cell);
    bool s2 = (l15 >= 2) && (c2 == cell);
    bool s4 = (l15 >= 4) && (c4 == cell);
    bool s8 = (l15 >= 8) && (c8 == cell);
    int cn = __shfl_down(cell, 1);
    bool tail = (l15 == 15) || (cn != cell);

#pragma unroll
    for (int i = 0; i < 32; ++i) {
        const float* wa = wf + OW1 + 8 * i;
        float a = wf[OB1 + 2 * i], b = wf[OB1 + 2 * i + 1];
        a = fmaf(wa[0], p.x, a); a = fmaf(wa[1], p.y, a);
        a = fmaf(wa[2], p.z, a); a = fmaf(wa[3], p.w, a);
        b = fmaf(wa[4], p.x, b); b = fmaf(wa[5], p.y, b);
        b = fmaf(wa[6], p.z, b); b = fmaf(wa[7], p.w, b);
        h1s[i * 256 + tid] = pk2(fmaxf(a, 0.0f), fmaxf(b, 0.0f));
    }
#pragma unroll 1
    for (int o0 = 0; o0 < 128; o0 += 16) {
        fv16 acc;
#pragma unroll
        for (int j = 0; j < 16; ++j) acc[j] = wf[OB2 + o0 + j];
#pragma unroll
        for (int r = 0; r < 32; ++r) {
            unsigned h1r = h1s[r * 256 + tid];
            const unsigned* wr = wu + OW2P + r * 128 + o0;
#pragma unroll
            for (int j = 0; j < 16; ++j) acc[j] = dot2(h1r, wr[j], acc[j]);
        }
#pragma unroll
        for (int j = 0; j < 16; j += 2)
            h2s[((o0 + j) >> 1) * 256 + tid] =
                pk2(fmaxf(acc[j], 0.f), fmaxf(acc[j + 1], 0.f));
    }

    int* ob = (int*)bev;
    long base0;
    if (layout == 0) base0 = (long)cell * 128;
    else             base0 = (long)(cell >> 14) * (128 * HW) + (cell & (HW - 1));

#pragma unroll 1
    for (int ch = 0; ch < 16; ++ch) {
        float a0=wf[OB3+ch*8+0], a1=wf[OB3+ch*8+1], a2=wf[OB3+ch*8+2], a3=wf[OB3+ch*8+3];
        float a4=wf[OB3+ch*8+4], a5=wf[OB3+ch*8+5], a6=wf[OB3+ch*8+6], a7=wf[OB3+ch*8+7];
        const unsigned* wq = wu + OW3P + ch * 512;
#pragma unroll
        for (int r = 0; r < 64; ++r) {
            unsigned h2r = h2s[r * 256 + tid];
            a0 = dot2(h2r, wq[r*8+0], a0); a1 = dot2(h2r, wq[r*8+1], a1);
            a2 = dot2(h2r, wq[r*8+2], a2); a3 = dot2(h2r, wq[r*8+3], a3);
            a4 = dot2(h2r, wq[r*8+4], a4); a5 = dot2(h2r, wq[r*8+5], a5);
            a6 = dot2(h2r, wq[r*8+6], a6); a7 = dot2(h2r, wq[r*8+7], a7);
        }
        float av[8] = {a0,a1,a2,a3,a4,a5,a6,a7};
#pragma unroll
        for (int j = 0; j < 8; ++j) {
            float aj = fmaxf(av[j], 0.0f);
            DPPMAX(aj, 1, s1); DPPMAX(aj, 2, s2);
            DPPMAX(aj, 4, s4); DPPMAX(aj, 8, s8);
            av[j] = aj;
        }
        if (tail && cell >= 0) {
            if (layout == 0) {
#pragma unroll
                for (int j = 0; j < 8; ++j)
                    atomicMax(ob + base0 + ch * 8 + j, __float_as_int(av[j]));
            } else {
#pragma unroll
                for (int j = 0; j < 8; ++j)
                    atomicMax(ob + base0 + (long)(ch * 8 + j) * HW, __float_as_int(av[j]));
            }
        }
    }
}

__global__ void transpose_bev_k(const float* __restrict__ bev, float* __restrict__ out)
{
    __shared__ float tile[32][129];
    const int tid = threadIdx.x;
    const int cell0 = blockIdx.x * 32;
#pragma unroll
    for (int k = 0; k < 16; ++k) {
        int idx = k * 256 + tid;
        int c = idx >> 7, f = idx & 127;
        tile[c][f] = bev[(size_t)(cell0 + c) * 128 + f];
    }
    __syncthreads();
    const int b = cell0 >> 14;
    const int cl0 = cell0 & (HW - 1);
#pragma unroll
    for (int k = 0; k < 16; ++k) {
        int idx = k * 256 + tid;
        int f = idx >> 5, c = idx & 31;
        out[(size_t)(b * 128 + f) * HW + cl0 + c] = tile[c][f];
    }
}

extern "C" void kernel_launch(void* const* d_in, const int* in_sizes, int n_in,
                              void* d_out, int out_size, void* d_ws, size_t ws_size,
                              hipStream_t stream)
{
    const float* points = (const float*)d_in[0];
    const float* W1 = (const float*)d_in[1];  const float* b1 = (const float*)d_in[2];
    const float* g1 = (const float*)d_in[3];  const float* be1 = (const float*)d_in[4];
    const float* m1 = (const float*)d_in[5];  const float* v1 = (const float*)d_in[6];
    const float* W2 = (const float*)d_in[7];  const float* b2 = (const float*)d_in[8];
    const float* g2 = (const float*)d_in[9];  const float* be2 = (const float*)d_in[10];
    const float* m2 = (const float*)d_in[11]; const float* v2 = (const float*)d_in[12];
    const float* W3 = (const float*)d_in[13]; const float* b3 = (const float*)d_in[14];
    const float* g3 = (const float*)d_in[15]; const float* be3 = (const float*)d_in[16];
    const float* m3 = (const float*)d_in[17]; const float* v3 = (const float*)d_in[18];

    float* wsf = (float*)d_ws;
    int*   wsi = (int*)d_ws;
    const size_t need_full = ((size_t)OFEATS + (size_t)NPTS * 64) * 4;  // ~129.3 MB
    const size_t need_bev  = ((size_t)OBEV + BEV_ELEMS) * 4;            // ~40 MB

    fold_weights_k<<<99, 256, 0, stream>>>(
        W1, b1, g1, be1, m1, v1, W2, b2, g2, be2, m2, v2, W3, b3, g3, be3, m3, v3, wsf);

    (void)hipMemsetAsync(wsi + OCNT, 0, 65536 * sizeof(int), stream);
    cells_hist_k<<<NPTS / 256, 256, 0, stream>>>(
        (const float4*)points, wsi + OCELLS, wsi + OCNT);
    scan_k<<<1, 1024, 0, stream>>>(wsi + OCNT, wsi + OOFF, wsi + ONV);
    scatter_idx_k<<<NPTS / 256, 256, 0, stream>>>(
        wsi + OCELLS, wsi + OOFF, wsi + OSIDX, wsi + OSCELL);

    if (ws_size >= need_full) {
        uint4* feats4 = (uint4*)(wsi + OFEATS);
        fused_mlp_k<<<NPTS / 64, 256, 0, stream>>>(
            (const float4*)points, wsf, wsi + OSIDX, wsi + ONV, feats4);
        reduce_k<<<BB * HW / 64, 256, 0, stream>>>(
            (const unsigned*)feats4, wsi + OOFF, wsi + OCNT, (float*)d_out);
    } else if (ws_size >= need_bev) {
        float* bev = wsf + OBEV;
        (void)hipMemsetAsync(bev, 0, (size_t)BEV_ELEMS * sizeof(float), stream);
        mlp_atomic_k<<<NPTS / 256, 256, 0, stream>>>(
            (const float4*)points, wsf, wsi + OSIDX, wsi + OSCELL, wsi + ONV, bev, 0);
        transpose_bev_k<<<HW * BB / 32, 256, 0, stream>>>(bev, (float*)d_out);
    } else {
        (void)hipMemsetAsync(d_out, 0, (size_t)out_size * sizeof(float), stream);
        mlp_atomic_k<<<NPTS / 256, 256, 0, stream>>>(
            (const float4*)points, wsf, wsi + OSIDX, wsi + OSCELL, wsi + ONV,
            (float*)d_out, 1);
    }
}

// Round 9
// 277.426 us; speedup vs baseline: 2.0493x; 1.0427x over previous
//
#include <hip/hip_runtime.h>
#include <hip/hip_fp16.h>

#define BB 4
#define NN 120000
#define FEAT 128
#define HH 128
#define WW 128
#define NPTS (BB*NN)
#define HW (HH*WW)

// ---- ws layout (4-byte element offsets) ----
#define OW1    0         // f32[256]  [o=64][i=4]
#define OB1    256       // f32[64]
#define OW2P   320       // u32[4096] packed half2 [r=32][o=128] (fallback)
#define OB2    4416      // f32[128]
#define OW3P   4544      // u32[8192] chunk layout (fallback)
#define OB3    12736     // f32[128]
#define OW3F   12864     // u32[8192] MFMA B-frag-linear W3 (verified r7/r8)
#define OW2F   21056     // u32[4096] MFMA B-frag-linear W2 (verified r8)
#define OCNT   25152     // i32[65536]
#define OOFF   90688     // i32[65536]
#define ONV    156224    // i32[1] (padded to 64)
#define OCELLS 156288    // i32[NPTS]
#define OSIDX  636288    // i32[NPTS]
#define OSCELL 1116288   // i32[NPTS]
#define OFEATS 1596288   // u32[NPTS*64] fp16 feats [slot][128]
#define OBEV   1596288   // fallback bev region (aliases OFEATS)
#define BEV_ELEMS (BB*HW*FEAT)

#if defined(__has_builtin)
#if __has_builtin(__builtin_amdgcn_fdot2)
#define HAS_FDOT2 1
#endif
#endif

typedef _Float16 hv2 __attribute__((ext_vector_type(2)));
typedef _Float16 f16x8 __attribute__((ext_vector_type(8)));
typedef float    f32x4 __attribute__((ext_vector_type(4)));
typedef float    fv16  __attribute__((ext_vector_type(16)));

__device__ __forceinline__ unsigned pk2(float a, float b) {
    __half2 h = __floats2half2_rn(a, b);
    return __builtin_bit_cast(unsigned, h);
}

__device__ __forceinline__ float dot2(unsigned a, unsigned b, float c) {
#ifdef HAS_FDOT2
    return __builtin_amdgcn_fdot2(__builtin_bit_cast(hv2, a),
                                  __builtin_bit_cast(hv2, b), c, false);
#else
    __half2 ah = __builtin_bit_cast(__half2, a), bh = __builtin_bit_cast(__half2, b);
    c = fmaf(__low2float(ah), __low2float(bh), c);
    return fmaf(__high2float(ah), __high2float(bh), c);
#endif
}

// post-ReLU fp16 (>=0) orders as unsigned halfwords
__device__ __forceinline__ unsigned hmax2u(unsigned a, unsigned b) {
    unsigned al = a & 0xFFFFu, bl = b & 0xFFFFu;
    unsigned ah = a & 0xFFFF0000u, bh = b & 0xFFFF0000u;
    unsigned lo = (al > bl) ? al : bl;
    unsigned hi = (ah > bh) ? ah : bh;
    return lo | hi;
}

// fp32 -> fp16 bits (low 16 of u32)
__device__ __forceinline__ unsigned h16(float v) {
    _Float16 h = (_Float16)v;
    return (unsigned)__builtin_bit_cast(unsigned short, h);
}

// ---------------- weight folding + fp16 packing (+ cnt zeroing) ----------------
__global__ void fold_weights_k(
    const float* __restrict__ W1, const float* __restrict__ b1,
    const float* __restrict__ g1, const float* __restrict__ be1,
    const float* __restrict__ m1, const float* __restrict__ v1,
    const float* __restrict__ W2, const float* __restrict__ b2,
    const float* __restrict__ g2, const float* __restrict__ be2,
    const float* __restrict__ m2, const float* __restrict__ v2,
    const float* __restrict__ W3, const float* __restrict__ b3,
    const float* __restrict__ g3, const float* __restrict__ be3,
    const float* __restrict__ m3, const float* __restrict__ v3,
    float* __restrict__ wf)
{
    unsigned* wu = (unsigned*)wf;
    int idx = blockIdx.x * 256 + threadIdx.x;
    const float EPSV = 1e-5f;
    if (idx < 256) {
        int o = idx >> 2;
        float s = g1[o] * rsqrtf(v1[o] + EPSV);
        wf[OW1 + idx] = W1[idx] * s;
    } else if (idx < 320) {
        int o = idx - 256;
        float s = g1[o] * rsqrtf(v1[o] + EPSV);
        wf[idx] = (b1[o] - m1[o]) * s + be1[o];
    } else if (idx < 4416) {
        int j = idx - OW2P;
        int r = j >> 7, o = j & 127;
        float s = g2[o] * rsqrtf(v2[o] + EPSV);
        wu[idx] = pk2(W2[o * 64 + 2 * r] * s, W2[o * 64 + 2 * r + 1] * s);
    } else if (idx < 4544) {
        int o = idx - OB2;
        float s = g2[o] * rsqrtf(v2[o] + EPSV);
        wf[idx] = (b2[o] - m2[o]) * s + be2[o];
    } else if (idx < 12736) {               // chunk layout (fallback path)
        int j = idx - OW3P;
        int ch = j >> 9, rem = j & 511;
        int r = rem >> 3, jj = rem & 7;
        int o = ch * 8 + jj;
        float s = g3[o] * rsqrtf(v3[o] + EPSV);
        wu[idx] = pk2(W3[o * 128 + 2 * r] * s, W3[o * 128 + 2 * r + 1] * s);
    } else if (idx < 12864) {
        int o = idx - OB3;
        float s = g3[o] * rsqrtf(v3[o] + EPSV);
        wf[idx] = (b3[o] - m3[o]) * s + be3[o];
    } else if (idx < 21056) {
        // W3 B-frag-linear: tile = nt*4+kt; lane l: n=(tile>>2)*16+(l&15),
        // k=(tile&3)*32+(l>>4)*8+j. u32 u: l=u>>2, q=u&3 -> j=2q,2q+1.
        int u = idx - OW3F;
        int tile = u >> 8, w = u & 255;
        int l = w >> 2, q = w & 3;
        int n = (tile >> 2) * 16 + (l & 15);
        int k = (tile & 3) * 32 + ((l >> 4) << 3) + 2 * q;
        float s = g3[n] * rsqrtf(v3[n] + EPSV);
        wu[idx] = pk2(W3[n * 128 + k] * s, W3[n * 128 + k + 1] * s);
    } else if (idx < 25152) {
        // W2 B-frag-linear: tile = nt*2+kt (K=64 -> 2 k-tiles)
        int u = idx - OW2F;
        int tile = u >> 8, w = u & 255;
        int l = w >> 2, q = w & 3;
        int n = (tile >> 1) * 16 + (l & 15);
        int k = (tile & 1) * 32 + ((l >> 4) << 3) + 2 * q;
        float s = g2[n] * rsqrtf(v2[n] + EPSV);
        wu[idx] = pk2(W2[n * 64 + k] * s, W2[n * 64 + k + 1] * s);
    } else if (idx < 25152 + 65536) {
        ((int*)wf)[OCNT + idx - 25152] = 0;   // zero histogram (saves a memset launch)
    }
}

// ---------------- sort-by-cell passes ----------------
__global__ __launch_bounds__(256)
void cells_hist_k(const float4* __restrict__ pts, int* __restrict__ cells,
                  int* __restrict__ cnt)
{
    int tid = blockIdx.x * 256 + threadIdx.x;
    float4 p = pts[tid];
    float xn = (p.x - (-50.0f)) / (50.0f - (-50.0f));
    float yn = (p.y - (-50.0f)) / (50.0f - (-50.0f));
    bool valid = (xn >= 0.0f) && (xn <= 1.0f) && (yn >= 0.0f) && (yn <= 1.0f);
    int gx = min(max((int)(xn * 127.0f), 0), 127);
    int gy = min(max((int)(yn * 127.0f), 0), 127);
    int b = tid / NN;
    int cell = valid ? (b * HW + gy * WW + gx) : -1;
    cells[tid] = cell;
    if (valid) atomicAdd(&cnt[cell], 1);
}

__global__ __launch_bounds__(1024)
void scan_k(const int* __restrict__ cnt, int* __restrict__ off, int* __restrict__ nvp)
{
    __shared__ int wsum[16];
    int t = threadIdx.x;
    int lane = t & 63, w = t >> 6;
    int base = t * 64;
    int s = 0;
#pragma unroll 8
    for (int j = 0; j < 64; ++j) s += cnt[base + j];
    int v = s;
#pragma unroll
    for (int d = 1; d < 64; d <<= 1) {
        int u = __shfl_up(v, d);
        if (lane >= d) v += u;
    }
    if (lane == 63) wsum[w] = v;
    __syncthreads();
    if (t == 0) {
        int r = 0;
#pragma unroll
        for (int k = 0; k < 16; ++k) { int x = wsum[k]; wsum[k] = r; r += x; }
        nvp[0] = r;
    }
    __syncthreads();
    int excl = (v - s) + wsum[w];
    int r = excl;
#pragma unroll 8
    for (int j = 0; j < 64; ++j) { off[base + j] = r; r += cnt[base + j]; }
}

__global__ __launch_bounds__(256)
void scatter_idx_k(const int* __restrict__ cells, int* __restrict__ off,
                   int* __restrict__ sidx, int* __restrict__ scell)
{
    int tid = blockIdx.x * 256 + threadIdx.x;
    int c = cells[tid];
    if (c >= 0) {
        int pos = atomicAdd(&off[c], 1);
        sidx[pos] = tid;
        scell[pos] = c;
    }
}

// ---------------- fused L1(VALU)+L2(MFMA)+L3(MFMA), single 16.9KB LDS buffer ----
// Wave = 16 points. LDS traffic intra-wave only (in-order per wave, no barriers).
// A-frag: A[m=lane&15][k=quad*8+j]; C/D: col=lane&15, row=quad*4+reg (verified).
// Row stride 132 halves = 66 u32: 4*66 % 32 = 8 -> q-groups hit disjoint bank octants.
__global__ __launch_bounds__(256)
void fused_mlp_k(const float4* __restrict__ pts, const float* __restrict__ wf,
                 const int* __restrict__ sidx, const int* __restrict__ nvp,
                 uint4* __restrict__ feats4)
{
    __shared__ __align__(16) _Float16 h2t[4][16 * 132];   // reused for L3 staging
    const unsigned* wu = (const unsigned*)wf;
    const uint4* bf2 = (const uint4*)(wu + OW2F);
    const uint4* bf3 = (const uint4*)(wu + OW3F);
    const int tid = threadIdx.x, wv = tid >> 6, l = tid & 63;
    const int nv = nvp[0];
    const int M0 = (blockIdx.x * 4 + wv) * 16;
    if (M0 >= nv) return;                       // wave-uniform
    const int l15 = l & 15, q = l >> 4;
    const int par = l15 & 1;

    const int slot = M0 + l15;
    const int pidx = (slot < nv) ? sidx[slot] : 0;
    float4 p = pts[pidx];

    // ---- layer 1 computed DIRECTLY in A2-frag order: f = kt*32 + q*8 + j
    // (each of the 4 q-lanes of a point covers disjoint features: no redundancy)
    uint4 a2[2];
#pragma unroll
    for (int kt = 0; kt < 2; ++kt) {
        unsigned w4[4];
#pragma unroll
        for (int t = 0; t < 4; ++t) {
            int f = kt * 32 + q * 8 + 2 * t;
            const float* wa = wf + OW1 + f * 4;
            float a = wf[OB1 + f], b = wf[OB1 + f + 1];
            a = fmaf(wa[0], p.x, a); a = fmaf(wa[1], p.y, a);
            a = fmaf(wa[2], p.z, a); a = fmaf(wa[3], p.w, a);
            b = fmaf(wa[4], p.x, b); b = fmaf(wa[5], p.y, b);
            b = fmaf(wa[6], p.z, b); b = fmaf(wa[7], p.w, b);
            w4[t] = pk2(fmaxf(a, 0.f), fmaxf(b, 0.f));
        }
        uint4 v; v.x = w4[0]; v.y = w4[1]; v.z = w4[2]; v.w = w4[3];
        a2[kt] = v;
    }

    unsigned* myh2 = (unsigned*)&h2t[wv][0];

    // ---- L2: MFMA -> DPP feature-pair pack -> 2 b32 stores/lane/nt
#pragma unroll
    for (int nt = 0; nt < 8; ++nt) {
        f32x4 acc = {0.f, 0.f, 0.f, 0.f};
        acc = __builtin_amdgcn_mfma_f32_16x16x32_f16(
            __builtin_bit_cast(f16x8, a2[0]),
            __builtin_bit_cast(f16x8, bf2[(nt * 2 + 0) * 64 + l]), acc, 0, 0, 0);
        acc = __builtin_amdgcn_mfma_f32_16x16x32_f16(
            __builtin_bit_cast(f16x8, a2[1]),
            __builtin_bit_cast(f16x8, bf2[(nt * 2 + 1) * 64 + l]), acc, 0, 0, 0);
        float bias = wf[OB2 + nt * 16 + l15];
        unsigned wrd[4];
#pragma unroll
        for (int rr = 0; rr < 4; ++rr) {
            unsigned h = h16(fmaxf(acc[rr] + bias, 0.f));
            unsigned nb = (unsigned)__builtin_amdgcn_update_dpp(
                0, (int)h, 0xB1 /*quad_perm[1,0,3,2]*/, 0xF, 0xF, false);
            wrd[rr] = par ? ((nb & 0xFFFFu) | (h << 16)) : (h | (nb << 16));
        }
        unsigned* base = myh2 + nt * 8 + (l15 >> 1);
#pragma unroll
        for (int i = 0; i < 2; ++i) {
            int rr = 2 * par + i;              // even lane: rows 0,1; odd: 2,3
            base[(q * 4 + rr) * 66] = wrd[rr];
        }
    }

    // ---- A3 fragments (in-order LDS per wave: stores above complete first)
    uint4 a3[4];
#pragma unroll
    for (int kt = 0; kt < 4; ++kt)
        a3[kt] = *(const uint4*)&h2t[wv][l15 * 132 + kt * 32 + q * 8];

    // ---- L3: MFMA -> same DPP pack -> store back into myh2 (h2 is dead)
#pragma unroll 2
    for (int nt = 0; nt < 8; ++nt) {
        f32x4 acc = {0.f, 0.f, 0.f, 0.f};
#pragma unroll
        for (int kt = 0; kt < 4; ++kt)
            acc = __builtin_amdgcn_mfma_f32_16x16x32_f16(
                __builtin_bit_cast(f16x8, a3[kt]),
                __builtin_bit_cast(f16x8, bf3[(nt * 4 + kt) * 64 + l]), acc, 0, 0, 0);
        float bias = wf[OB3 + nt * 16 + l15];
        unsigned wrd[4];
#pragma unroll
        for (int rr = 0; rr < 4; ++rr) {
            unsigned h = h16(fmaxf(acc[rr] + bias, 0.f));
            unsigned nb = (unsigned)__builtin_amdgcn_update_dpp(
                0, (int)h, 0xB1, 0xF, 0xF, false);
            wrd[rr] = par ? ((nb & 0xFFFFu) | (h << 16)) : (h | (nb << 16));
        }
        unsigned* base = myh2 + nt * 8 + (l15 >> 1);
#pragma unroll
        for (int i = 0; i < 2; ++i) {
            int rr = 2 * par + i;
            base[(q * 4 + rr) * 66] = wrd[rr];
        }
    }

    // ---- coalesced writeout: 4KB contiguous per wave
    const int pt = l >> 2, part = l & 3;
#pragma unroll
    for (int i = 0; i < 4; ++i) {
        uint4 vv = *(const uint4*)&h2t[wv][pt * 132 + (part * 4 + i) * 8];
        feats4[(size_t)(M0 + pt) * 16 + part * 4 + i] = vv;
    }
}

// ---------------- per-cell max-reduce, uint4 / 4-row loads ----------------
__global__ __launch_bounds__(256)
void reduce_k(const unsigned* __restrict__ feats, const int* __restrict__ off,
              const int* __restrict__ cnt, float* __restrict__ out)
{
    __shared__ float tile[128][65];
    const int tid = threadIdx.x;
    const int w = tid >> 6, l = tid & 63;
    const int l15 = l & 15, lq = l >> 4;
    const int c0 = blockIdx.x * 64;
    const uint4* f4 = (const uint4*)feats;

#pragma unroll 2
    for (int cc = 0; cc < 16; ++cc) {
        int c = c0 + w * 16 + cc;
        int n = cnt[c];
        int start = off[c] - n;                // off advanced to run end by scatter
        uint4 m = {0u, 0u, 0u, 0u};
        const uint4* fp = f4 + (size_t)(start + lq) * 16 + l15;
#pragma unroll 1
        for (int p = 0; p < n; p += 4) {
            if (p + lq < n) {
                uint4 v = fp[(size_t)p * 16];
                m.x = hmax2u(m.x, v.x); m.y = hmax2u(m.y, v.y);
                m.z = hmax2u(m.z, v.z); m.w = hmax2u(m.w, v.w);
            }
        }
#pragma unroll
        for (int d = 16; d <= 32; d <<= 1) {
            m.x = hmax2u(m.x, (unsigned)__shfl_xor((int)m.x, d));
            m.y = hmax2u(m.y, (unsigned)__shfl_xor((int)m.y, d));
            m.z = hmax2u(m.z, (unsigned)__shfl_xor((int)m.z, d));
            m.w = hmax2u(m.w, (unsigned)__shfl_xor((int)m.w, d));
        }
        if (lq == 0) {
            int f0 = 8 * l15, cl = w * 16 + cc;
            __half2 hx = __builtin_bit_cast(__half2, m.x);
            __half2 hy = __builtin_bit_cast(__half2, m.y);
            __half2 hz = __builtin_bit_cast(__half2, m.z);
            __half2 hw = __builtin_bit_cast(__half2, m.w);
            tile[f0 + 0][cl] = __low2float(hx); tile[f0 + 1][cl] = __high2float(hx);
            tile[f0 + 2][cl] = __low2float(hy); tile[f0 + 3][cl] = __high2float(hy);
            tile[f0 + 4][cl] = __low2float(hz); tile[f0 + 5][cl] = __high2float(hz);
            tile[f0 + 6][cl] = __low2float(hw); tile[f0 + 7][cl] = __high2float(hw);
        }
    }
    __syncthreads();
    const int b = c0 >> 14;
    const int cxy = c0 & (HW - 1);
#pragma unroll 4
    for (int k = 0; k < 32; ++k) {
        int idx = k * 256 + tid;
        int f = idx >> 6, cl = idx & 63;
        out[((size_t)(b * 128 + f)) * HW + cxy + cl] = tile[f][cl];
    }
}

// ---------------- small-ws fallback: sorted+run-merged atomics ----------------
#define DPPMAX(A, D, S) { \
    float _pv = __int_as_float(__builtin_amdgcn_update_dpp( \
        0, __float_as_int(A), 0x110 | (D), 0xF, 0xF, false)); \
    A = (S) ? fmaxf(A, _pv) : A; }

__global__ __launch_bounds__(256)
void mlp_atomic_k(const float4* __restrict__ pts, const float* __restrict__ wf,
                  const int* __restrict__ sidx, const int* __restrict__ scell,
                  const int* __restrict__ nvp, float* __restrict__ bev, int layout)
{
    __shared__ unsigned h1s[32 * 256];
    __shared__ unsigned h2s[64 * 256];
    const unsigned* wu = (const unsigned*)wf;
    const int tid = threadIdx.x;
    const int slot = blockIdx.x * 256 + tid;
    const int nv = nvp[0];
    if ((slot & ~63) >= nv) return;
    const int lane = tid & 63;
    const int l15 = lane & 15;
    const bool live = slot < nv;
    const int cell = live ? scell[slot] : -1;
    const int pidx = live ? sidx[slot] : 0;
    float4 p = pts[pidx];

    int c1 = __shfl_up(cell, 1), c2 = __shfl_up(cell, 2);
    int c4 = __shfl_up(cell, 4), c8 = __shfl_up(cell, 8);
    bool s1 = (l15 >= 1) && (c1 == cell);
    bool s2 = (l15 >= 2) && (c2 == cell);
    bool s4 = (l15 >= 4) && (c4 == cell);
    bool s8 = (l15 >= 8) && (c8 == cell);
    int cn = __shfl_down(cell, 1);
    bool tail = (l15 == 15) || (cn != cell);

#pragma unroll
    for (int i = 0; i < 32; ++i) {
        const float* wa = wf + OW1 + 8 * i;
        float a = wf[OB1 + 2 * i], b = wf[OB1 + 2 * i + 1];
        a = fmaf(wa[0], p.x, a); a = fmaf(wa[1], p.y, a);
        a = fmaf(wa[2], p.z, a); a = fmaf(wa[3], p.w, a);
        b = fmaf(wa[4], p.x, b); b = fmaf(wa[5], p.y, b);
        b = fmaf(wa[6], p.z, b); b = fmaf(wa[7], p.w, b);
        h1s[i * 256 + tid] = pk2(fmaxf(a, 0.0f), fmaxf(b, 0.0f));
    }
#pragma unroll 1
    for (int o0 = 0; o0 < 128; o0 += 16) {
        fv16 acc;
#pragma unroll
        for (int j = 0; j < 16; ++j) acc[j] = wf[OB2 + o0 + j];
#pragma unroll
        for (int r = 0; r < 32; ++r) {
            unsigned h1r = h1s[r * 256 + tid];
            const unsigned* wr = wu + OW2P + r * 128 + o0;
#pragma unroll
            for (int j = 0; j < 16; ++j) acc[j] = dot2(h1r, wr[j], acc[j]);
        }
#pragma unroll
        for (int j = 0; j < 16; j += 2)
            h2s[((o0 + j) >> 1) * 256 + tid] =
                pk2(fmaxf(acc[j], 0.f), fmaxf(acc[j + 1], 0.f));
    }

    int* ob = (int*)bev;
    long base0;
    if (layout == 0) base0 = (long)cell * 128;
    else             base0 = (long)(cell >> 14) * (128 * HW) + (cell & (HW - 1));

#pragma unroll 1
    for (int ch = 0; ch < 16; ++ch) {
        float a0=wf[OB3+ch*8+0], a1=wf[OB3+ch*8+1], a2=wf[OB3+ch*8+2], a3=wf[OB3+ch*8+3];
        float a4=wf[OB3+ch*8+4], a5=wf[OB3+ch*8+5], a6=wf[OB3+ch*8+6], a7=wf[OB3+ch*8+7];
        const unsigned* wq = wu + OW3P + ch * 512;
#pragma unroll
        for (int r = 0; r < 64; ++r) {
            unsigned h2r = h2s[r * 256 + tid];
            a0 = dot2(h2r, wq[r*8+0], a0); a1 = dot2(h2r, wq[r*8+1], a1);
            a2 = dot2(h2r, wq[r*8+2], a2); a3 = dot2(h2r, wq[r*8+3], a3);
            a4 = dot2(h2r, wq[r*8+4], a4); a5 = dot2(h2r, wq[r*8+5], a5);
            a6 = dot2(h2r, wq[r*8+6], a6); a7 = dot2(h2r, wq[r*8+7], a7);
        }
        float av[8] = {a0,a1,a2,a3,a4,a5,a6,a7};
#pragma unroll
        for (int j = 0; j < 8; ++j) {
            float aj = fmaxf(av[j], 0.0f);
            DPPMAX(aj, 1, s1); DPPMAX(aj, 2, s2);
            DPPMAX(aj, 4, s4); DPPMAX(aj, 8, s8);
            av[j] = aj;
        }
        if (tail && cell >= 0) {
            if (layout == 0) {
#pragma unroll
                for (int j = 0; j < 8; ++j)
                    atomicMax(ob + base0 + ch * 8 + j, __float_as_int(av[j]));
            } else {
#pragma unroll
                for (int j = 0; j < 8; ++j)
                    atomicMax(ob + base0 + (long)(ch * 8 + j) * HW, __float_as_int(av[j]));
            }
        }
    }
}

__global__ void transpose_bev_k(const float* __restrict__ bev, float* __restrict__ out)
{
    __shared__ float tile[32][129];
    const int tid = threadIdx.x;
    const int cell0 = blockIdx.x * 32;
#pragma unroll
    for (int k = 0; k < 16; ++k) {
        int idx = k * 256 + tid;
        int c = idx >> 7, f = idx & 127;
        tile[c][f] = bev[(size_t)(cell0 + c) * 128 + f];
    }
    __syncthreads();
    const int b = cell0 >> 14;
    const int cl0 = cell0 & (HW - 1);
#pragma unroll
    for (int k = 0; k < 16; ++k) {
        int idx = k * 256 + tid;
        int f = idx >> 5, c = idx & 31;
        out[(size_t)(b * 128 + f) * HW + cl0 + c] = tile[c][f];
    }
}

extern "C" void kernel_launch(void* const* d_in, const int* in_sizes, int n_in,
                              void* d_out, int out_size, void* d_ws, size_t ws_size,
                              hipStream_t stream)
{
    const float* points = (const float*)d_in[0];
    const float* W1 = (const float*)d_in[1];  const float* b1 = (const float*)d_in[2];
    const float* g1 = (const float*)d_in[3];  const float* be1 = (const float*)d_in[4];
    const float* m1 = (const float*)d_in[5];  const float* v1 = (const float*)d_in[6];
    const float* W2 = (const float*)d_in[7];  const float* b2 = (const float*)d_in[8];
    const float* g2 = (const float*)d_in[9];  const float* be2 = (const float*)d_in[10];
    const float* m2 = (const float*)d_in[11]; const float* v2 = (const float*)d_in[12];
    const float* W3 = (const float*)d_in[13]; const float* b3 = (const float*)d_in[14];
    const float* g3 = (const float*)d_in[15]; const float* be3 = (const float*)d_in[16];
    const float* m3 = (const float*)d_in[17]; const float* v3 = (const float*)d_in[18];

    float* wsf = (float*)d_ws;
    int*   wsi = (int*)d_ws;
    const size_t need_full = ((size_t)OFEATS + (size_t)NPTS * 64) * 4;  // ~129.3 MB
    const size_t need_bev  = ((size_t)OBEV + BEV_ELEMS) * 4;            // ~40 MB

    // fold grid covers 25152 weight items + 65536 cnt zeroes
    fold_weights_k<<<(25152 + 65536 + 255) / 256, 256, 0, stream>>>(
        W1, b1, g1, be1, m1, v1, W2, b2, g2, be2, m2, v2, W3, b3, g3, be3, m3, v3, wsf);

    cells_hist_k<<<NPTS / 256, 256, 0, stream>>>(
        (const float4*)points, wsi + OCELLS, wsi + OCNT);
    scan_k<<<1, 1024, 0, stream>>>(wsi + OCNT, wsi + OOFF, wsi + ONV);
    scatter_idx_k<<<NPTS / 256, 256, 0, stream>>>(
        wsi + OCELLS, wsi + OOFF, wsi + OSIDX, wsi + OSCELL);

    if (ws_size >= need_full) {
        uint4* feats4 = (uint4*)(wsi + OFEATS);
        fused_mlp_k<<<NPTS / 64, 256, 0, stream>>>(
            (const float4*)points, wsf, wsi + OSIDX, wsi + ONV, feats4);
        reduce_k<<<BB * HW / 64, 256, 0, stream>>>(
            (const unsigned*)feats4, wsi + OOFF, wsi + OCNT, (float*)d_out);
    } else if (ws_size >= need_bev) {
        float* bev = wsf + OBEV;
        (void)hipMemsetAsync(bev, 0, (size_t)BEV_ELEMS * sizeof(float), stream);
        mlp_atomic_k<<<NPTS / 256, 256, 0, stream>>>(
            (const float4*)points, wsf, wsi + OSIDX, wsi + OSCELL, wsi + ONV, bev, 0);
        transpose_bev_k<<<HW * BB / 32, 256, 0, stream>>>(bev, (float*)d_out);
    } else {
        (void)hipMemsetAsync(d_out, 0, (size_t)out_size * sizeof(float), stream);
        mlp_atomic_k<<<NPTS / 256, 256, 0, stream>>>(
            (const float4*)points, wsf, wsi + OSIDX, wsi + OSCELL, wsi + ONV,
            (float*)d_out, 1);
    }
}